// Round 2
// baseline (1545.528 us; speedup 1.0000x reference)
//
#include <hip/hip_runtime.h>

#define N_NODES 100000
#define N_EDGES 800000
#define DF 64
#define NGRAPH 512
#define LDIM 192   // L * D

// ---------------------------------------------------------------------------
// CSR build: histogram of row[], exclusive scan, fill col_sorted
// ---------------------------------------------------------------------------
__global__ __launch_bounds__(256) void hist_kernel(
    const int* __restrict__ ei, int* __restrict__ deg)
{
    int e = blockIdx.x * 256 + threadIdx.x;
    if (e < N_EDGES) atomicAdd(&deg[ei[e]], 1);
}

__global__ __launch_bounds__(1024) void scan_kernel(
    const int* __restrict__ deg, int* __restrict__ off)
{
    __shared__ int partial[1024];
    int tid = threadIdx.x;
    const int CH = (N_NODES + 1023) / 1024;   // 98
    int base = tid * CH;
    int s = 0;
    for (int i = 0; i < CH; ++i) {
        int idx = base + i;
        if (idx < N_NODES) s += deg[idx];
    }
    partial[tid] = s;
    __syncthreads();
    for (int ofs = 1; ofs < 1024; ofs <<= 1) {
        int v = (tid >= ofs) ? partial[tid - ofs] : 0;
        __syncthreads();
        partial[tid] += v;
        __syncthreads();
    }
    int run = (tid == 0) ? 0 : partial[tid - 1];
    for (int i = 0; i < CH; ++i) {
        int idx = base + i;
        if (idx < N_NODES) { off[idx] = run; run += deg[idx]; }
        else if (idx == N_NODES) { off[idx] = run; }
    }
}

__global__ __launch_bounds__(256) void fill_kernel(
    const int* __restrict__ ei, const int* __restrict__ off,
    int* __restrict__ cursor, int* __restrict__ colS)
{
    int e = blockIdx.x * 256 + threadIdx.x;
    if (e >= N_EDGES) return;
    int r = ei[e];
    int c = ei[N_EDGES + e];
    int pos = atomicAdd(&cursor[r], 1);
    colS[off[r] + pos] = c;
}

// ---------------------------------------------------------------------------
// Fused GIN layer: CSR gather + (1+eps)*h + MLP(Linear-ReLU-Linear-ReLU) +
// conv bias + ReLU, writes z3, accumulates BN stats (double).
// Block = 4 waves; each wave owns 4 nodes per tile -> no inner barriers.
// ---------------------------------------------------------------------------
__global__ __launch_bounds__(256) void gin_layer_kernel(
    const float* __restrict__ h,
    const int* __restrict__ off,
    const int* __restrict__ colS,
    float* __restrict__ zout,
    const float* __restrict__ W1, const float* __restrict__ b1,
    const float* __restrict__ W2, const float* __restrict__ b2,
    const float* __restrict__ gin_eps, const float* __restrict__ gin_bias,
    double* __restrict__ stats)
{
    __shared__ float W1s[64 * 64];
    __shared__ float W2s[64 * 64];
    __shared__ float zs[16][64];
    __shared__ float z1s[16][64];
    __shared__ double red[2][4][64];

    int tid = threadIdx.x;
    for (int i = tid; i < 4096; i += 256) { W1s[i] = W1[i]; W2s[i] = W2[i]; }
    int w = tid >> 6;     // wave 0..3
    int f = tid & 63;
    float b1f = b1[f], b2f = b2[f], gbf = gin_bias[f];
    float epsf = 1.0f + gin_eps[0];
    double lsum = 0.0, lsq = 0.0;
    __syncthreads();

    const int ntiles = N_NODES / 16;   // 6250
    for (int tile = blockIdx.x; tile < ntiles; tile += gridDim.x) {
        int n0 = tile * 16 + w * 4;
        // ---- phase A: gather agg for 4 nodes (wave-private LDS rows) ----
        #pragma unroll
        for (int m = 0; m < 4; ++m) {
            int node = n0 + m;
            int s = off[node], e2 = off[node + 1];
            float acc = 0.0f;
            for (int i = s; i < e2; i += 64) {
                int cnt = min(e2 - i, 64);
                int cidx = (i + f < e2) ? colS[i + f] : 0;
                for (int j = 0; j < cnt; ++j) {
                    int c = __shfl(cidx, j, 64);
                    acc += h[c * DF + f];
                }
            }
            zs[w * 4 + m][f] = epsf * h[node * DF + f] + acc;
        }

        // ---- phase B: MLP1 (4 nodes per wave, W amortized) ----
        float acc1[4];
        #pragma unroll
        for (int m = 0; m < 4; ++m) acc1[m] = b1f;
        #pragma unroll
        for (int kk = 0; kk < 16; ++kk) {
            float4 zv[4];
            #pragma unroll
            for (int m = 0; m < 4; ++m)
                zv[m] = *(const float4*)&zs[w * 4 + m][kk * 4];
            float wv0 = W1s[(kk * 4 + 0) * 64 + f];
            float wv1 = W1s[(kk * 4 + 1) * 64 + f];
            float wv2 = W1s[(kk * 4 + 2) * 64 + f];
            float wv3 = W1s[(kk * 4 + 3) * 64 + f];
            #pragma unroll
            for (int m = 0; m < 4; ++m)
                acc1[m] += zv[m].x * wv0 + zv[m].y * wv1 +
                           zv[m].z * wv2 + zv[m].w * wv3;
        }
        #pragma unroll
        for (int m = 0; m < 4; ++m)
            z1s[w * 4 + m][f] = fmaxf(acc1[m], 0.0f);

        // ---- phase C: MLP2 + bias + relu + store + stats ----
        float acc2[4];
        #pragma unroll
        for (int m = 0; m < 4; ++m) acc2[m] = b2f;
        #pragma unroll
        for (int kk = 0; kk < 16; ++kk) {
            float4 zv[4];
            #pragma unroll
            for (int m = 0; m < 4; ++m)
                zv[m] = *(const float4*)&z1s[w * 4 + m][kk * 4];
            float wv0 = W2s[(kk * 4 + 0) * 64 + f];
            float wv1 = W2s[(kk * 4 + 1) * 64 + f];
            float wv2 = W2s[(kk * 4 + 2) * 64 + f];
            float wv3 = W2s[(kk * 4 + 3) * 64 + f];
            #pragma unroll
            for (int m = 0; m < 4; ++m)
                acc2[m] += zv[m].x * wv0 + zv[m].y * wv1 +
                           zv[m].z * wv2 + zv[m].w * wv3;
        }
        #pragma unroll
        for (int m = 0; m < 4; ++m) {
            float z3 = fmaxf(fmaxf(acc2[m], 0.0f) + gbf, 0.0f);
            zout[(n0 + m) * DF + f] = z3;
            lsum += (double)z3;
            lsq += (double)z3 * (double)z3;
        }
    }

    red[0][w][f] = lsum;
    red[1][w][f] = lsq;
    __syncthreads();
    if (w == 0) {
        double s = red[0][0][f] + red[0][1][f] + red[0][2][f] + red[0][3][f];
        double q = red[1][0][f] + red[1][1][f] + red[1][2][f] + red[1][3][f];
        atomicAdd(&stats[f], s);
        atomicAdd(&stats[64 + f], q);
    }
}

// ---------------------------------------------------------------------------
__global__ void finalize_kernel(
    const double* __restrict__ stats,
    const float* __restrict__ gamma,
    const float* __restrict__ beta,
    float* __restrict__ scale,
    float* __restrict__ shift)
{
    int f = threadIdx.x;
    double mean = stats[f] * (1.0 / N_NODES);
    double var = stats[64 + f] * (1.0 / N_NODES) - mean * mean;
    double inv = (double)gamma[f] / sqrt(var + 1e-5);
    scale[f] = (float)inv;
    shift[f] = (float)((double)beta[f] - mean * inv);
}

// ---------------------------------------------------------------------------
// BN apply (in-place, float4) + pool into per-graph accumulator
// ---------------------------------------------------------------------------
__global__ __launch_bounds__(256) void bn_pool_kernel(
    float* __restrict__ z,
    const float* __restrict__ scale,
    const float* __restrict__ shift,
    const int* __restrict__ batch,
    float* __restrict__ pooled,
    int layerOff)
{
    int idx = blockIdx.x * 256 + threadIdx.x;   // one per (node, 4-feature quad)
    const int total = N_NODES * 16;
    if (idx >= total) return;
    int node = idx >> 4;
    int q = idx & 15;
    float4 v = ((const float4*)z)[idx];
    float4 s = ((const float4*)scale)[q];
    float4 sh = ((const float4*)shift)[q];
    v.x = v.x * s.x + sh.x;
    v.y = v.y * s.y + sh.y;
    v.z = v.z * s.z + sh.z;
    v.w = v.w * s.w + sh.w;
    ((float4*)z)[idx] = v;
    int g = batch[node];
    float* p = &pooled[g * LDIM + layerOff + q * 4];
    unsafeAtomicAdd(p + 0, v.x);
    unsafeAtomicAdd(p + 1, v.y);
    unsafeAtomicAdd(p + 2, v.z);
    unsafeAtomicAdd(p + 3, v.w);
}

// ---------------------------------------------------------------------------
__global__ __launch_bounds__(192) void proj_kernel(
    const float* __restrict__ in,
    const float* __restrict__ W,
    const float* __restrict__ b,
    float* __restrict__ out,
    int do_relu)
{
    __shared__ float rowS[LDIM];
    int r = blockIdx.x;
    int c = threadIdx.x;
    rowS[c] = in[r * LDIM + c];
    __syncthreads();
    float acc = b[c];
    #pragma unroll 4
    for (int k = 0; k < LDIM; ++k) acc += rowS[k] * W[k * LDIM + c];
    out[r * LDIM + c] = do_relu ? fmaxf(acc, 0.0f) : acc;
}

// ---------------------------------------------------------------------------
extern "C" void kernel_launch(void* const* d_in, const int* in_sizes, int n_in,
                              void* d_out, int out_size, void* d_ws, size_t ws_size,
                              hipStream_t stream)
{
    const float* x        = (const float*)d_in[0];
    const int*   ei       = (const int*)d_in[1];
    const int*   batch    = (const int*)d_in[2];
    const float* W1       = (const float*)d_in[3];
    const float* b1       = (const float*)d_in[4];
    const float* W2       = (const float*)d_in[5];
    const float* b2       = (const float*)d_in[6];
    const float* gin_eps  = (const float*)d_in[7];
    const float* gin_bias = (const float*)d_in[8];
    const float* gamma    = (const float*)d_in[9];
    const float* beta     = (const float*)d_in[10];
    const float* Wp1      = (const float*)d_in[11];
    const float* bp1      = (const float*)d_in[12];
    const float* Wp2      = (const float*)d_in[13];
    const float* bp2      = (const float*)d_in[14];
    float* out = (float*)d_out;

    // workspace layout
    float* bufA = (float*)d_ws;                            // N*64
    float* bufB = bufA + (size_t)N_NODES * DF;             // N*64
    double* stats = (double*)(bufB + (size_t)N_NODES * DF);// 128 doubles
    float* scale = (float*)(stats + 128);                  // 64
    float* shift = scale + 64;                             // 64
    float* pooled = shift + 64;                            // NGRAPH*LDIM
    float* hidden = pooled + (size_t)NGRAPH * LDIM;        // NGRAPH*LDIM
    int* deg  = (int*)(hidden + (size_t)NGRAPH * LDIM);    // N (also cursor)
    int* off  = deg + N_NODES;                             // N+1
    int* colS = off + N_NODES + 1;                         // E

    // ---- CSR build (once, reused for all 3 layers) ----
    hipMemsetAsync(deg, 0, N_NODES * sizeof(int), stream);
    hist_kernel<<<(N_EDGES + 255) / 256, 256, 0, stream>>>(ei, deg);
    scan_kernel<<<1, 1024, 0, stream>>>(deg, off);
    hipMemsetAsync(deg, 0, N_NODES * sizeof(int), stream);  // reuse as cursor
    fill_kernel<<<(N_EDGES + 255) / 256, 256, 0, stream>>>(ei, off, deg, colS);

    hipMemsetAsync(pooled, 0, (size_t)NGRAPH * LDIM * sizeof(float), stream);

    const float* hin = x;
    float* bufs[2] = {bufA, bufB};
    for (int l = 0; l < 3; ++l) {
        float* zl = bufs[l & 1];
        hipMemsetAsync(stats, 0, 128 * sizeof(double), stream);

        gin_layer_kernel<<<2048, 256, 0, stream>>>(
            hin, off, colS, zl,
            W1 + l * 4096, b1 + l * 64, W2 + l * 4096, b2 + l * 64,
            gin_eps + l, gin_bias + l * 64, stats);

        finalize_kernel<<<1, 64, 0, stream>>>(stats, gamma + l * 64,
                                              beta + l * 64, scale, shift);

        bn_pool_kernel<<<(N_NODES * 16 + 255) / 256, 256, 0, stream>>>(
            zl, scale, shift, batch, pooled, l * 64);

        hin = zl;
    }

    proj_kernel<<<NGRAPH, LDIM, 0, stream>>>(pooled, Wp1, bp1, hidden, 1);
    proj_kernel<<<NGRAPH, LDIM, 0, stream>>>(hidden, Wp2, bp2, out, 0);
}

// Round 3
// 742.085 us; speedup vs baseline: 2.0827x; 2.0827x over previous
//
#include <hip/hip_runtime.h>

#define N_NODES 100000
#define N_EDGES 800000
#define DF 64
#define NGRAPH 512
#define LDIM 192   // L * D
#define BN_EPS 1e-5

// ---------------------------------------------------------------------------
// CSR build: histogram of row[], exclusive scan, fill col_sorted
// ---------------------------------------------------------------------------
__global__ __launch_bounds__(256) void hist_kernel(
    const int* __restrict__ ei, int* __restrict__ deg)
{
    int e = blockIdx.x * 256 + threadIdx.x;
    if (e < N_EDGES) atomicAdd(&deg[ei[e]], 1);
}

__global__ __launch_bounds__(1024) void scan_kernel(
    const int* __restrict__ deg, int* __restrict__ off)
{
    __shared__ int partial[1024];
    int tid = threadIdx.x;
    const int CH = (N_NODES + 1023) / 1024;   // 98
    int base = tid * CH;
    int s = 0;
    for (int i = 0; i < CH; ++i) {
        int idx = base + i;
        if (idx < N_NODES) s += deg[idx];
    }
    partial[tid] = s;
    __syncthreads();
    for (int ofs = 1; ofs < 1024; ofs <<= 1) {
        int v = (tid >= ofs) ? partial[tid - ofs] : 0;
        __syncthreads();
        partial[tid] += v;
        __syncthreads();
    }
    int run = (tid == 0) ? 0 : partial[tid - 1];
    for (int i = 0; i < CH; ++i) {
        int idx = base + i;
        if (idx < N_NODES) { off[idx] = run; run += deg[idx]; }
        else if (idx == N_NODES) { off[idx] = run; }
    }
}

__global__ __launch_bounds__(256) void fill_kernel(
    const int* __restrict__ ei, const int* __restrict__ off,
    int* __restrict__ cursor, int* __restrict__ colS)
{
    int e = blockIdx.x * 256 + threadIdx.x;
    if (e >= N_EDGES) return;
    int r = ei[e];
    int c = ei[N_EDGES + e];
    int pos = atomicAdd(&cursor[r], 1);
    colS[off[r] + pos] = c;
}

// ---------------------------------------------------------------------------
// Graph segment starts: gstart[g] = lower_bound(batch, g); gstart[NG] = N
// ---------------------------------------------------------------------------
__global__ __launch_bounds__(256) void gstart_kernel(
    const int* __restrict__ batch, int* __restrict__ gstart)
{
    int g = blockIdx.x * 256 + threadIdx.x;
    if (g > NGRAPH) return;
    if (g == NGRAPH) { gstart[g] = N_NODES; return; }
    int lo = 0, hi = N_NODES;
    while (lo < hi) {
        int mid = (lo + hi) >> 1;
        if (batch[mid] < g) lo = mid + 1; else hi = mid;
    }
    gstart[g] = lo;
}

// ---------------------------------------------------------------------------
// Fused GIN layer: CSR gather + (1+eps)*h + MLP(Linear-ReLU-Linear-ReLU) +
// conv bias + ReLU, writes z3, accumulates BN stats (double).
// Block = 4 waves; each wave owns 4 nodes per tile -> no inner barriers.
// ---------------------------------------------------------------------------
__global__ __launch_bounds__(256) void gin_layer_kernel(
    const float* __restrict__ h,
    const int* __restrict__ off,
    const int* __restrict__ colS,
    float* __restrict__ zout,
    const float* __restrict__ W1, const float* __restrict__ b1,
    const float* __restrict__ W2, const float* __restrict__ b2,
    const float* __restrict__ gin_eps, const float* __restrict__ gin_bias,
    double* __restrict__ stats)
{
    __shared__ float W1s[64 * 64];
    __shared__ float W2s[64 * 64];
    __shared__ float zs[16][64];
    __shared__ float z1s[16][64];
    __shared__ double red[2][4][64];

    int tid = threadIdx.x;
    for (int i = tid; i < 4096; i += 256) { W1s[i] = W1[i]; W2s[i] = W2[i]; }
    int w = tid >> 6;     // wave 0..3
    int f = tid & 63;
    float b1f = b1[f], b2f = b2[f], gbf = gin_bias[f];
    float epsf = 1.0f + gin_eps[0];
    double lsum = 0.0, lsq = 0.0;
    __syncthreads();

    const int ntiles = N_NODES / 16;   // 6250
    for (int tile = blockIdx.x; tile < ntiles; tile += gridDim.x) {
        int n0 = tile * 16 + w * 4;
        // ---- phase A: gather agg for 4 nodes (4 loads kept in flight) ----
        #pragma unroll
        for (int m = 0; m < 4; ++m) {
            int node = n0 + m;
            int s = off[node], e2 = off[node + 1];
            float acc = 0.0f;
            for (int i = s; i < e2; i += 64) {
                int cnt = e2 - i; if (cnt > 64) cnt = 64;
                int cidx = (i + f < e2) ? colS[i + f] : 0;
                int j = 0;
                for (; j + 4 <= cnt; j += 4) {
                    int c0 = __shfl(cidx, j, 64);
                    int c1 = __shfl(cidx, j + 1, 64);
                    int c2 = __shfl(cidx, j + 2, 64);
                    int c3 = __shfl(cidx, j + 3, 64);
                    float v0 = h[c0 * DF + f];
                    float v1 = h[c1 * DF + f];
                    float v2 = h[c2 * DF + f];
                    float v3 = h[c3 * DF + f];
                    acc += v0; acc += v1; acc += v2; acc += v3;
                }
                for (; j < cnt; ++j) {
                    int c = __shfl(cidx, j, 64);
                    acc += h[c * DF + f];
                }
            }
            zs[w * 4 + m][f] = epsf * h[node * DF + f] + acc;
        }

        // ---- phase B: MLP1 (4 nodes per wave, W amortized) ----
        float acc1[4];
        #pragma unroll
        for (int m = 0; m < 4; ++m) acc1[m] = b1f;
        #pragma unroll
        for (int kk = 0; kk < 16; ++kk) {
            float4 zv[4];
            #pragma unroll
            for (int m = 0; m < 4; ++m)
                zv[m] = *(const float4*)&zs[w * 4 + m][kk * 4];
            float wv0 = W1s[(kk * 4 + 0) * 64 + f];
            float wv1 = W1s[(kk * 4 + 1) * 64 + f];
            float wv2 = W1s[(kk * 4 + 2) * 64 + f];
            float wv3 = W1s[(kk * 4 + 3) * 64 + f];
            #pragma unroll
            for (int m = 0; m < 4; ++m)
                acc1[m] += zv[m].x * wv0 + zv[m].y * wv1 +
                           zv[m].z * wv2 + zv[m].w * wv3;
        }
        #pragma unroll
        for (int m = 0; m < 4; ++m)
            z1s[w * 4 + m][f] = fmaxf(acc1[m], 0.0f);

        // ---- phase C: MLP2 + bias + relu + store + stats ----
        float acc2[4];
        #pragma unroll
        for (int m = 0; m < 4; ++m) acc2[m] = b2f;
        #pragma unroll
        for (int kk = 0; kk < 16; ++kk) {
            float4 zv[4];
            #pragma unroll
            for (int m = 0; m < 4; ++m)
                zv[m] = *(const float4*)&z1s[w * 4 + m][kk * 4];
            float wv0 = W2s[(kk * 4 + 0) * 64 + f];
            float wv1 = W2s[(kk * 4 + 1) * 64 + f];
            float wv2 = W2s[(kk * 4 + 2) * 64 + f];
            float wv3 = W2s[(kk * 4 + 3) * 64 + f];
            #pragma unroll
            for (int m = 0; m < 4; ++m)
                acc2[m] += zv[m].x * wv0 + zv[m].y * wv1 +
                           zv[m].z * wv2 + zv[m].w * wv3;
        }
        #pragma unroll
        for (int m = 0; m < 4; ++m) {
            float z3 = fmaxf(fmaxf(acc2[m], 0.0f) + gbf, 0.0f);
            zout[(n0 + m) * DF + f] = z3;
            lsum += (double)z3;
            lsq += (double)z3 * (double)z3;
        }
    }

    red[0][w][f] = lsum;
    red[1][w][f] = lsq;
    __syncthreads();
    if (w == 0) {
        double s = red[0][0][f] + red[0][1][f] + red[0][2][f] + red[0][3][f];
        double q = red[1][0][f] + red[1][1][f] + red[1][2][f] + red[1][3][f];
        atomicAdd(&stats[f], s);
        atomicAdd(&stats[64 + f], q);
    }
}

// ---------------------------------------------------------------------------
// Per-graph segmented BN-apply + h write + pool. One block per graph.
// Computes BN scale/shift from stats in-block (no separate finalize launch,
// no atomics: batch is sorted so each graph owns a contiguous node range).
// ---------------------------------------------------------------------------
__global__ __launch_bounds__(256) void bn_pool_kernel(
    const float* __restrict__ z,
    const double* __restrict__ stats,
    const float* __restrict__ gamma,
    const float* __restrict__ beta,
    const int* __restrict__ gstart,
    float* __restrict__ hout,
    float* __restrict__ pooled,
    int layerOff)
{
    __shared__ float red[4][64];
    int g = blockIdx.x;
    int tid = threadIdx.x;
    int w = tid >> 6, f = tid & 63;

    double mean = stats[f] * (1.0 / N_NODES);
    double var = stats[64 + f] * (1.0 / N_NODES) - mean * mean;
    double inv = (double)gamma[f] / sqrt(var + BN_EPS);
    float sc = (float)inv;
    float sh = (float)((double)beta[f] - mean * inv);

    int s = gstart[g], e = gstart[g + 1];
    float acc = 0.0f;
    for (int node = s + w; node < e; node += 4) {
        float v = z[node * DF + f] * sc + sh;
        hout[node * DF + f] = v;
        acc += v;
    }
    red[w][f] = acc;
    __syncthreads();
    if (w == 0)
        pooled[g * LDIM + layerOff + f] =
            red[0][f] + red[1][f] + red[2][f] + red[3][f];
}

// ---------------------------------------------------------------------------
__global__ __launch_bounds__(192) void proj_kernel(
    const float* __restrict__ in,
    const float* __restrict__ W,
    const float* __restrict__ b,
    float* __restrict__ out,
    int do_relu)
{
    __shared__ float rowS[LDIM];
    int r = blockIdx.x;
    int c = threadIdx.x;
    rowS[c] = in[r * LDIM + c];
    __syncthreads();
    float acc = b[c];
    #pragma unroll 4
    for (int k = 0; k < LDIM; ++k) acc += rowS[k] * W[k * LDIM + c];
    out[r * LDIM + c] = do_relu ? fmaxf(acc, 0.0f) : acc;
}

// ---------------------------------------------------------------------------
extern "C" void kernel_launch(void* const* d_in, const int* in_sizes, int n_in,
                              void* d_out, int out_size, void* d_ws, size_t ws_size,
                              hipStream_t stream)
{
    const float* x        = (const float*)d_in[0];
    const int*   ei       = (const int*)d_in[1];
    const int*   batch    = (const int*)d_in[2];
    const float* W1       = (const float*)d_in[3];
    const float* b1       = (const float*)d_in[4];
    const float* W2       = (const float*)d_in[5];
    const float* b2       = (const float*)d_in[6];
    const float* gin_eps  = (const float*)d_in[7];
    const float* gin_bias = (const float*)d_in[8];
    const float* gamma    = (const float*)d_in[9];
    const float* beta     = (const float*)d_in[10];
    const float* Wp1      = (const float*)d_in[11];
    const float* bp1      = (const float*)d_in[12];
    const float* Wp2      = (const float*)d_in[13];
    const float* bp2      = (const float*)d_in[14];
    float* out = (float*)d_out;

    // workspace layout
    float* bufA = (float*)d_ws;                             // N*64 (z)
    float* bufB = bufA + (size_t)N_NODES * DF;              // N*64 (h)
    double* stats = (double*)(bufB + (size_t)N_NODES * DF); // 3*128 doubles
    float* pooled = (float*)(stats + 3 * 128);              // NGRAPH*LDIM
    float* hidden = pooled + (size_t)NGRAPH * LDIM;         // NGRAPH*LDIM
    int* gstart = (int*)(hidden + (size_t)NGRAPH * LDIM);   // NGRAPH+1
    int* deg  = gstart + NGRAPH + 1;                        // N (also cursor)
    int* off  = deg + N_NODES;                              // N+1
    int* colS = off + N_NODES + 1;                          // E

    // ---- CSR build + graph segments (once, reused for all 3 layers) ----
    hipMemsetAsync(deg, 0, N_NODES * sizeof(int), stream);
    hist_kernel<<<(N_EDGES + 255) / 256, 256, 0, stream>>>(ei, deg);
    scan_kernel<<<1, 1024, 0, stream>>>(deg, off);
    hipMemsetAsync(deg, 0, N_NODES * sizeof(int), stream);  // reuse as cursor
    fill_kernel<<<(N_EDGES + 255) / 256, 256, 0, stream>>>(ei, off, deg, colS);
    gstart_kernel<<<3, 256, 0, stream>>>(batch, gstart);
    hipMemsetAsync(stats, 0, 3 * 128 * sizeof(double), stream);

    const float* hin = x;
    for (int l = 0; l < 3; ++l) {
        gin_layer_kernel<<<2048, 256, 0, stream>>>(
            hin, off, colS, bufA,
            W1 + l * 4096, b1 + l * 64, W2 + l * 4096, b2 + l * 64,
            gin_eps + l, gin_bias + l * 64, stats + l * 128);

        bn_pool_kernel<<<NGRAPH, 256, 0, stream>>>(
            bufA, stats + l * 128, gamma + l * 64, beta + l * 64,
            gstart, bufB, pooled, l * 64);

        hin = bufB;
    }

    proj_kernel<<<NGRAPH, LDIM, 0, stream>>>(pooled, Wp1, bp1, hidden, 1);
    proj_kernel<<<NGRAPH, LDIM, 0, stream>>>(hidden, Wp2, bp2, out, 0);
}

// Round 4
// 627.468 us; speedup vs baseline: 2.4631x; 1.1827x over previous
//
#include <hip/hip_runtime.h>

#define N_NODES 100000
#define N_EDGES 800000
#define DF 64
#define NGRAPH 512
#define LDIM 192   // L * D
#define BN_EPS 1e-5
#define SCAN_BLOCKS 98   // ceil(100000/1024)

// ---------------------------------------------------------------------------
// CSR build: histogram of row[], 3-phase parallel exclusive scan, fill
// ---------------------------------------------------------------------------
__global__ __launch_bounds__(256) void hist_kernel(
    const int* __restrict__ ei, int* __restrict__ deg)
{
    int e = blockIdx.x * 256 + threadIdx.x;
    if (e < N_EDGES) atomicAdd(&deg[ei[e]], 1);
}

__global__ __launch_bounds__(1024) void block_sum_kernel(
    const int* __restrict__ deg, int* __restrict__ blockSum)
{
    __shared__ int ws[16];
    int b = blockIdx.x, tid = threadIdx.x;
    int idx = b * 1024 + tid;
    int v = (idx < N_NODES) ? deg[idx] : 0;
    #pragma unroll
    for (int o = 32; o > 0; o >>= 1) v += __shfl_down(v, o, 64);
    if ((tid & 63) == 0) ws[tid >> 6] = v;
    __syncthreads();
    if (tid == 0) {
        int s = 0;
        #pragma unroll
        for (int i = 0; i < 16; ++i) s += ws[i];
        blockSum[b] = s;
    }
}

__global__ __launch_bounds__(128) void scan_partials_kernel(
    const int* __restrict__ blockSum, int* __restrict__ blockOff)
{
    __shared__ int buf[SCAN_BLOCKS];
    int tid = threadIdx.x;
    if (tid < SCAN_BLOCKS) buf[tid] = blockSum[tid];
    __syncthreads();
    if (tid == 0) {
        int run = 0;
        for (int i = 0; i < SCAN_BLOCKS; ++i) {
            int v = buf[i]; buf[i] = run; run += v;
        }
    }
    __syncthreads();
    if (tid < SCAN_BLOCKS) blockOff[tid] = buf[tid];
}

__global__ __launch_bounds__(1024) void scan_final_kernel(
    const int* __restrict__ deg, const int* __restrict__ blockOff,
    int* __restrict__ off)
{
    __shared__ int buf[1024];
    int b = blockIdx.x, tid = threadIdx.x;
    int idx = b * 1024 + tid;
    int v = (idx < N_NODES) ? deg[idx] : 0;
    buf[tid] = v;
    __syncthreads();
    for (int ofs = 1; ofs < 1024; ofs <<= 1) {
        int t = (tid >= ofs) ? buf[tid - ofs] : 0;
        __syncthreads();
        buf[tid] += t;
        __syncthreads();
    }
    if (idx <= N_NODES) off[idx] = buf[tid] - v + blockOff[b];
}

__global__ __launch_bounds__(256) void fill_kernel(
    const int* __restrict__ ei, const int* __restrict__ off,
    int* __restrict__ cursor, int* __restrict__ colS)
{
    int e = blockIdx.x * 256 + threadIdx.x;
    if (e >= N_EDGES) return;
    int r = ei[e];
    int c = ei[N_EDGES + e];
    int pos = atomicAdd(&cursor[r], 1);
    colS[off[r] + pos] = c;
}

// ---------------------------------------------------------------------------
// Graph segment starts: gstart[g] = lower_bound(batch, g); gstart[NG] = N
// ---------------------------------------------------------------------------
__global__ __launch_bounds__(256) void gstart_kernel(
    const int* __restrict__ batch, int* __restrict__ gstart)
{
    int g = blockIdx.x * 256 + threadIdx.x;
    if (g > NGRAPH) return;
    if (g == NGRAPH) { gstart[g] = N_NODES; return; }
    int lo = 0, hi = N_NODES;
    while (lo < hi) {
        int mid = (lo + hi) >> 1;
        if (batch[mid] < g) lo = mid + 1; else hi = mid;
    }
    gstart[g] = lo;
}

// ---------------------------------------------------------------------------
// Fused GIN layer: CSR gather + (1+eps)*h + MLP(Linear-ReLU-Linear-ReLU) +
// conv bias + ReLU, writes z3, accumulates BN stats (double).
// Block = 4 waves; each wave owns 4 nodes per tile -> no inner barriers.
// Edge-index loads are wave-uniform -> compiler emits scalar loads.
// ---------------------------------------------------------------------------
__global__ __launch_bounds__(256) void gin_layer_kernel(
    const float* __restrict__ h,
    const int* __restrict__ off,
    const int* __restrict__ colS,
    float* __restrict__ zout,
    const float* __restrict__ W1, const float* __restrict__ b1,
    const float* __restrict__ W2, const float* __restrict__ b2,
    const float* __restrict__ gin_eps, const float* __restrict__ gin_bias,
    double* __restrict__ stats)
{
    __shared__ float W1s[64 * 64];
    __shared__ float W2s[64 * 64];
    __shared__ float zs[16][64];
    __shared__ float z1s[16][64];
    __shared__ double red[2][4][64];

    int tid = threadIdx.x;
    for (int i = tid; i < 4096; i += 256) { W1s[i] = W1[i]; W2s[i] = W2[i]; }
    int w = tid >> 6;     // wave 0..3
    int f = tid & 63;
    float b1f = b1[f], b2f = b2[f], gbf = gin_bias[f];
    float epsf = 1.0f + gin_eps[0];
    double lsum = 0.0, lsq = 0.0;
    __syncthreads();

    const int ntiles = N_NODES / 16;   // 6250
    for (int tile = blockIdx.x; tile < ntiles; tile += gridDim.x) {
        int n0 = tile * 16 + w * 4;
        // ---- phase A: gather (uniform scalar index loads, 8 in flight) ----
        #pragma unroll
        for (int m = 0; m < 4; ++m) {
            int node = n0 + m;
            int s = off[node], e2 = off[node + 1];
            float hn = h[node * DF + f];
            float acc = 0.0f;
            int i = s;
            for (; i + 8 <= e2; i += 8) {
                int c0 = colS[i + 0], c1 = colS[i + 1];
                int c2 = colS[i + 2], c3 = colS[i + 3];
                int c4 = colS[i + 4], c5 = colS[i + 5];
                int c6 = colS[i + 6], c7 = colS[i + 7];
                float v0 = h[c0 * DF + f], v1 = h[c1 * DF + f];
                float v2 = h[c2 * DF + f], v3 = h[c3 * DF + f];
                float v4 = h[c4 * DF + f], v5 = h[c5 * DF + f];
                float v6 = h[c6 * DF + f], v7 = h[c7 * DF + f];
                acc += ((v0 + v1) + (v2 + v3)) + ((v4 + v5) + (v6 + v7));
            }
            for (; i < e2; ++i) acc += h[colS[i] * DF + f];
            zs[w * 4 + m][f] = epsf * hn + acc;
        }

        // ---- phase B: MLP1 (4 nodes per wave, W amortized) ----
        float acc1[4];
        #pragma unroll
        for (int m = 0; m < 4; ++m) acc1[m] = b1f;
        #pragma unroll
        for (int kk = 0; kk < 16; ++kk) {
            float4 zv[4];
            #pragma unroll
            for (int m = 0; m < 4; ++m)
                zv[m] = *(const float4*)&zs[w * 4 + m][kk * 4];
            float wv0 = W1s[(kk * 4 + 0) * 64 + f];
            float wv1 = W1s[(kk * 4 + 1) * 64 + f];
            float wv2 = W1s[(kk * 4 + 2) * 64 + f];
            float wv3 = W1s[(kk * 4 + 3) * 64 + f];
            #pragma unroll
            for (int m = 0; m < 4; ++m)
                acc1[m] += zv[m].x * wv0 + zv[m].y * wv1 +
                           zv[m].z * wv2 + zv[m].w * wv3;
        }
        #pragma unroll
        for (int m = 0; m < 4; ++m)
            z1s[w * 4 + m][f] = fmaxf(acc1[m], 0.0f);

        // ---- phase C: MLP2 + bias + relu + store + stats ----
        float acc2[4];
        #pragma unroll
        for (int m = 0; m < 4; ++m) acc2[m] = b2f;
        #pragma unroll
        for (int kk = 0; kk < 16; ++kk) {
            float4 zv[4];
            #pragma unroll
            for (int m = 0; m < 4; ++m)
                zv[m] = *(const float4*)&z1s[w * 4 + m][kk * 4];
            float wv0 = W2s[(kk * 4 + 0) * 64 + f];
            float wv1 = W2s[(kk * 4 + 1) * 64 + f];
            float wv2 = W2s[(kk * 4 + 2) * 64 + f];
            float wv3 = W2s[(kk * 4 + 3) * 64 + f];
            #pragma unroll
            for (int m = 0; m < 4; ++m)
                acc2[m] += zv[m].x * wv0 + zv[m].y * wv1 +
                           zv[m].z * wv2 + zv[m].w * wv3;
        }
        #pragma unroll
        for (int m = 0; m < 4; ++m) {
            float z3 = fmaxf(fmaxf(acc2[m], 0.0f) + gbf, 0.0f);
            zout[(n0 + m) * DF + f] = z3;
            lsum += (double)z3;
            lsq += (double)z3 * (double)z3;
        }
    }

    red[0][w][f] = lsum;
    red[1][w][f] = lsq;
    __syncthreads();
    if (w == 0) {
        double s = red[0][0][f] + red[0][1][f] + red[0][2][f] + red[0][3][f];
        double q = red[1][0][f] + red[1][1][f] + red[1][2][f] + red[1][3][f];
        atomicAdd(&stats[f], s);
        atomicAdd(&stats[64 + f], q);
    }
}

// ---------------------------------------------------------------------------
// Per-graph segmented BN-apply + h write + pool. One block per graph.
// ---------------------------------------------------------------------------
__global__ __launch_bounds__(256) void bn_pool_kernel(
    const float* __restrict__ z,
    const double* __restrict__ stats,
    const float* __restrict__ gamma,
    const float* __restrict__ beta,
    const int* __restrict__ gstart,
    float* __restrict__ hout,
    float* __restrict__ pooled,
    int layerOff)
{
    __shared__ float red[4][64];
    int g = blockIdx.x;
    int tid = threadIdx.x;
    int w = tid >> 6, f = tid & 63;

    double mean = stats[f] * (1.0 / N_NODES);
    double var = stats[64 + f] * (1.0 / N_NODES) - mean * mean;
    double inv = (double)gamma[f] / sqrt(var + BN_EPS);
    float sc = (float)inv;
    float sh = (float)((double)beta[f] - mean * inv);

    int s = gstart[g], e = gstart[g + 1];
    float acc = 0.0f;
    for (int node = s + w; node < e; node += 4) {
        float v = z[node * DF + f] * sc + sh;
        hout[node * DF + f] = v;
        acc += v;
    }
    red[w][f] = acc;
    __syncthreads();
    if (w == 0)
        pooled[g * LDIM + layerOff + f] =
            red[0][f] + red[1][f] + red[2][f] + red[3][f];
}

// ---------------------------------------------------------------------------
__global__ __launch_bounds__(192) void proj_kernel(
    const float* __restrict__ in,
    const float* __restrict__ W,
    const float* __restrict__ b,
    float* __restrict__ out,
    int do_relu)
{
    __shared__ float rowS[LDIM];
    int r = blockIdx.x;
    int c = threadIdx.x;
    rowS[c] = in[r * LDIM + c];
    __syncthreads();
    float acc = b[c];
    #pragma unroll 4
    for (int k = 0; k < LDIM; ++k) acc += rowS[k] * W[k * LDIM + c];
    out[r * LDIM + c] = do_relu ? fmaxf(acc, 0.0f) : acc;
}

// ---------------------------------------------------------------------------
extern "C" void kernel_launch(void* const* d_in, const int* in_sizes, int n_in,
                              void* d_out, int out_size, void* d_ws, size_t ws_size,
                              hipStream_t stream)
{
    const float* x        = (const float*)d_in[0];
    const int*   ei       = (const int*)d_in[1];
    const int*   batch    = (const int*)d_in[2];
    const float* W1       = (const float*)d_in[3];
    const float* b1       = (const float*)d_in[4];
    const float* W2       = (const float*)d_in[5];
    const float* b2       = (const float*)d_in[6];
    const float* gin_eps  = (const float*)d_in[7];
    const float* gin_bias = (const float*)d_in[8];
    const float* gamma    = (const float*)d_in[9];
    const float* beta     = (const float*)d_in[10];
    const float* Wp1      = (const float*)d_in[11];
    const float* bp1      = (const float*)d_in[12];
    const float* Wp2      = (const float*)d_in[13];
    const float* bp2      = (const float*)d_in[14];
    float* out = (float*)d_out;

    // workspace layout
    float* bufA = (float*)d_ws;                             // N*64 (z)
    float* bufB = bufA + (size_t)N_NODES * DF;              // N*64 (h)
    double* stats = (double*)(bufB + (size_t)N_NODES * DF); // 3*128 doubles
    float* pooled = (float*)(stats + 3 * 128);              // NGRAPH*LDIM
    float* hidden = pooled + (size_t)NGRAPH * LDIM;         // NGRAPH*LDIM
    int* gstart = (int*)(hidden + (size_t)NGRAPH * LDIM);   // NGRAPH+1
    int* deg  = gstart + NGRAPH + 1;                        // N (also cursor)
    int* off  = deg + N_NODES;                              // N+1
    int* colS = off + N_NODES + 1;                          // E
    int* blockSum = colS + N_EDGES;                         // SCAN_BLOCKS
    int* blockOff = blockSum + SCAN_BLOCKS;                 // SCAN_BLOCKS

    // ---- CSR build + graph segments (once, reused for all 3 layers) ----
    hipMemsetAsync(deg, 0, N_NODES * sizeof(int), stream);
    hist_kernel<<<(N_EDGES + 255) / 256, 256, 0, stream>>>(ei, deg);
    block_sum_kernel<<<SCAN_BLOCKS, 1024, 0, stream>>>(deg, blockSum);
    scan_partials_kernel<<<1, 128, 0, stream>>>(blockSum, blockOff);
    scan_final_kernel<<<SCAN_BLOCKS, 1024, 0, stream>>>(deg, blockOff, off);
    hipMemsetAsync(deg, 0, N_NODES * sizeof(int), stream);  // reuse as cursor
    fill_kernel<<<(N_EDGES + 255) / 256, 256, 0, stream>>>(ei, off, deg, colS);
    gstart_kernel<<<3, 256, 0, stream>>>(batch, gstart);
    hipMemsetAsync(stats, 0, 3 * 128 * sizeof(double), stream);

    const float* hin = x;
    for (int l = 0; l < 3; ++l) {
        gin_layer_kernel<<<2048, 256, 0, stream>>>(
            hin, off, colS, bufA,
            W1 + l * 4096, b1 + l * 64, W2 + l * 4096, b2 + l * 64,
            gin_eps + l, gin_bias + l * 64, stats + l * 128);

        bn_pool_kernel<<<NGRAPH, 256, 0, stream>>>(
            bufA, stats + l * 128, gamma + l * 64, beta + l * 64,
            gstart, bufB, pooled, l * 64);

        hin = bufB;
    }

    proj_kernel<<<NGRAPH, LDIM, 0, stream>>>(pooled, Wp1, bp1, hidden, 1);
    proj_kernel<<<NGRAPH, LDIM, 0, stream>>>(hidden, Wp2, bp2, out, 0);
}

// Round 5
// 562.261 us; speedup vs baseline: 2.7488x; 1.1160x over previous
//
#include <hip/hip_runtime.h>

#define N_NODES 100000
#define N_EDGES 800000
#define DF 64
#define NGRAPH 512
#define LDIM 192   // L * D
#define BN_EPS 1e-5
#define SCAN_BLOCKS 98   // ceil(100000/1024)

// ---------------------------------------------------------------------------
// CSR build: histogram of row[], 3-phase parallel exclusive scan, fill
// ---------------------------------------------------------------------------
__global__ __launch_bounds__(256) void hist_kernel(
    const int* __restrict__ ei, int* __restrict__ deg)
{
    int e = blockIdx.x * 256 + threadIdx.x;
    if (e < N_EDGES) atomicAdd(&deg[ei[e]], 1);
}

__global__ __launch_bounds__(1024) void block_sum_kernel(
    const int* __restrict__ deg, int* __restrict__ blockSum)
{
    __shared__ int ws[16];
    int b = blockIdx.x, tid = threadIdx.x;
    int idx = b * 1024 + tid;
    int v = (idx < N_NODES) ? deg[idx] : 0;
    #pragma unroll
    for (int o = 32; o > 0; o >>= 1) v += __shfl_down(v, o, 64);
    if ((tid & 63) == 0) ws[tid >> 6] = v;
    __syncthreads();
    if (tid == 0) {
        int s = 0;
        #pragma unroll
        for (int i = 0; i < 16; ++i) s += ws[i];
        blockSum[b] = s;
    }
}

__global__ __launch_bounds__(128) void scan_partials_kernel(
    const int* __restrict__ blockSum, int* __restrict__ blockOff)
{
    __shared__ int buf[SCAN_BLOCKS];
    int tid = threadIdx.x;
    if (tid < SCAN_BLOCKS) buf[tid] = blockSum[tid];
    __syncthreads();
    if (tid == 0) {
        int run = 0;
        for (int i = 0; i < SCAN_BLOCKS; ++i) {
            int v = buf[i]; buf[i] = run; run += v;
        }
    }
    __syncthreads();
    if (tid < SCAN_BLOCKS) blockOff[tid] = buf[tid];
}

__global__ __launch_bounds__(1024) void scan_final_kernel(
    const int* __restrict__ deg, const int* __restrict__ blockOff,
    int* __restrict__ off)
{
    __shared__ int buf[1024];
    int b = blockIdx.x, tid = threadIdx.x;
    int idx = b * 1024 + tid;
    int v = (idx < N_NODES) ? deg[idx] : 0;
    buf[tid] = v;
    __syncthreads();
    for (int ofs = 1; ofs < 1024; ofs <<= 1) {
        int t = (tid >= ofs) ? buf[tid - ofs] : 0;
        __syncthreads();
        buf[tid] += t;
        __syncthreads();
    }
    if (idx <= N_NODES) off[idx] = buf[tid] - v + blockOff[b];
}

__global__ __launch_bounds__(256) void fill_kernel(
    const int* __restrict__ ei, const int* __restrict__ off,
    int* __restrict__ cursor, int* __restrict__ colS)
{
    int e = blockIdx.x * 256 + threadIdx.x;
    if (e >= N_EDGES) return;
    int r = ei[e];
    int c = ei[N_EDGES + e];
    int pos = atomicAdd(&cursor[r], 1);
    colS[off[r] + pos] = c;
}

// ---------------------------------------------------------------------------
// Graph segment starts: gstart[g] = lower_bound(batch, g); gstart[NG] = N
// ---------------------------------------------------------------------------
__global__ __launch_bounds__(256) void gstart_kernel(
    const int* __restrict__ batch, int* __restrict__ gstart)
{
    int g = blockIdx.x * 256 + threadIdx.x;
    if (g > NGRAPH) return;
    if (g == NGRAPH) { gstart[g] = N_NODES; return; }
    int lo = 0, hi = N_NODES;
    while (lo < hi) {
        int mid = (lo + hi) >> 1;
        if (batch[mid] < g) lo = mid + 1; else hi = mid;
    }
    gstart[g] = lo;
}

// ---------------------------------------------------------------------------
// Fused GIN layer: CSR gather + (1+eps)*h + MLP(Linear-ReLU-Linear-ReLU) +
// conv bias + ReLU, writes z3, accumulates BN stats (double).
// Weights read from global (L1/L2-resident, 32KB) -> tiny LDS -> occupancy.
// Masked 8-wide gather: no serial tail. No barriers in the main loop.
// ---------------------------------------------------------------------------
__global__ __launch_bounds__(256) void gin_layer_kernel(
    const float* __restrict__ h,
    const int* __restrict__ off,
    const int* __restrict__ colS,
    float* __restrict__ zout,
    const float* __restrict__ W1, const float* __restrict__ b1,
    const float* __restrict__ W2, const float* __restrict__ b2,
    const float* __restrict__ gin_eps, const float* __restrict__ gin_bias,
    double* __restrict__ stats)
{
    __shared__ float zs[16][64];        // z in phase B, overwritten by z1 for C
    __shared__ double red[2][4][64];

    int tid = threadIdx.x;
    int w = tid >> 6;     // wave 0..3
    int f = tid & 63;
    float b1f = b1[f], b2f = b2[f], gbf = gin_bias[f];
    float epsf = 1.0f + gin_eps[0];
    double lsum = 0.0, lsq = 0.0;

    const int ntiles = N_NODES / 16;   // 6250
    for (int tile = blockIdx.x; tile < ntiles; tile += gridDim.x) {
        int n0 = tile * 16 + w * 4;

        // ---- phase A: masked 8-wide gather (8 loads always in flight) ----
        #pragma unroll
        for (int m = 0; m < 4; ++m) {
            int node = n0 + m;
            int s = off[node], e2 = off[node + 1];
            float hn = h[node * DF + f];
            float acc = 0.0f;
            for (int i = s; i < e2; i += 8) {
                int cc[8];
                float vv[8];
                #pragma unroll
                for (int j = 0; j < 8; ++j) {
                    int idx = i + j;
                    cc[j] = colS[idx < e2 ? idx : s];
                }
                #pragma unroll
                for (int j = 0; j < 8; ++j)
                    vv[j] = h[cc[j] * DF + f];
                #pragma unroll
                for (int j = 0; j < 8; ++j)
                    acc += (i + j < e2) ? vv[j] : 0.0f;
            }
            zs[w * 4 + m][f] = epsf * hn + acc;
        }

        // ---- phase B: MLP1 (weights from global, L1-resident) ----
        float acc1[4];
        #pragma unroll
        for (int m = 0; m < 4; ++m) acc1[m] = b1f;
        #pragma unroll
        for (int kk = 0; kk < 16; ++kk) {
            float4 zv[4];
            #pragma unroll
            for (int m = 0; m < 4; ++m)
                zv[m] = *(const float4*)&zs[w * 4 + m][kk * 4];
            float wv0 = W1[(kk * 4 + 0) * 64 + f];
            float wv1 = W1[(kk * 4 + 1) * 64 + f];
            float wv2 = W1[(kk * 4 + 2) * 64 + f];
            float wv3 = W1[(kk * 4 + 3) * 64 + f];
            #pragma unroll
            for (int m = 0; m < 4; ++m)
                acc1[m] += zv[m].x * wv0 + zv[m].y * wv1 +
                           zv[m].z * wv2 + zv[m].w * wv3;
        }
        // z1 overwrites zs rows (wave-private; all z reads issued above)
        #pragma unroll
        for (int m = 0; m < 4; ++m)
            zs[w * 4 + m][f] = fmaxf(acc1[m], 0.0f);

        // ---- phase C: MLP2 + bias + relu + store + stats ----
        float acc2[4];
        #pragma unroll
        for (int m = 0; m < 4; ++m) acc2[m] = b2f;
        #pragma unroll
        for (int kk = 0; kk < 16; ++kk) {
            float4 zv[4];
            #pragma unroll
            for (int m = 0; m < 4; ++m)
                zv[m] = *(const float4*)&zs[w * 4 + m][kk * 4];
            float wv0 = W2[(kk * 4 + 0) * 64 + f];
            float wv1 = W2[(kk * 4 + 1) * 64 + f];
            float wv2 = W2[(kk * 4 + 2) * 64 + f];
            float wv3 = W2[(kk * 4 + 3) * 64 + f];
            #pragma unroll
            for (int m = 0; m < 4; ++m)
                acc2[m] += zv[m].x * wv0 + zv[m].y * wv1 +
                           zv[m].z * wv2 + zv[m].w * wv3;
        }
        #pragma unroll
        for (int m = 0; m < 4; ++m) {
            float z3 = fmaxf(fmaxf(acc2[m], 0.0f) + gbf, 0.0f);
            zout[(n0 + m) * DF + f] = z3;
            lsum += (double)z3;
            lsq += (double)z3 * (double)z3;
        }
    }

    red[0][w][f] = lsum;
    red[1][w][f] = lsq;
    __syncthreads();
    if (w == 0) {
        double s = red[0][0][f] + red[0][1][f] + red[0][2][f] + red[0][3][f];
        double q = red[1][0][f] + red[1][1][f] + red[1][2][f] + red[1][3][f];
        atomicAdd(&stats[f], s);
        atomicAdd(&stats[64 + f], q);
    }
}

// ---------------------------------------------------------------------------
// Per-graph segmented BN-apply + h write + pool. One block per graph.
// ---------------------------------------------------------------------------
__global__ __launch_bounds__(256) void bn_pool_kernel(
    const float* __restrict__ z,
    const double* __restrict__ stats,
    const float* __restrict__ gamma,
    const float* __restrict__ beta,
    const int* __restrict__ gstart,
    float* __restrict__ hout,
    float* __restrict__ pooled,
    int layerOff)
{
    __shared__ float red[4][64];
    int g = blockIdx.x;
    int tid = threadIdx.x;
    int w = tid >> 6, f = tid & 63;

    double mean = stats[f] * (1.0 / N_NODES);
    double var = stats[64 + f] * (1.0 / N_NODES) - mean * mean;
    double inv = (double)gamma[f] / sqrt(var + BN_EPS);
    float sc = (float)inv;
    float sh = (float)((double)beta[f] - mean * inv);

    int s = gstart[g], e = gstart[g + 1];
    float acc = 0.0f;
    for (int node = s + w; node < e; node += 4) {
        float v = z[node * DF + f] * sc + sh;
        hout[node * DF + f] = v;
        acc += v;
    }
    red[w][f] = acc;
    __syncthreads();
    if (w == 0)
        pooled[g * LDIM + layerOff + f] =
            red[0][f] + red[1][f] + red[2][f] + red[3][f];
}

// ---------------------------------------------------------------------------
__global__ __launch_bounds__(192) void proj_kernel(
    const float* __restrict__ in,
    const float* __restrict__ W,
    const float* __restrict__ b,
    float* __restrict__ out,
    int do_relu)
{
    __shared__ float rowS[LDIM];
    int r = blockIdx.x;
    int c = threadIdx.x;
    rowS[c] = in[r * LDIM + c];
    __syncthreads();
    float acc = b[c];
    #pragma unroll 4
    for (int k = 0; k < LDIM; ++k) acc += rowS[k] * W[k * LDIM + c];
    out[r * LDIM + c] = do_relu ? fmaxf(acc, 0.0f) : acc;
}

// ---------------------------------------------------------------------------
extern "C" void kernel_launch(void* const* d_in, const int* in_sizes, int n_in,
                              void* d_out, int out_size, void* d_ws, size_t ws_size,
                              hipStream_t stream)
{
    const float* x        = (const float*)d_in[0];
    const int*   ei       = (const int*)d_in[1];
    const int*   batch    = (const int*)d_in[2];
    const float* W1       = (const float*)d_in[3];
    const float* b1       = (const float*)d_in[4];
    const float* W2       = (const float*)d_in[5];
    const float* b2       = (const float*)d_in[6];
    const float* gin_eps  = (const float*)d_in[7];
    const float* gin_bias = (const float*)d_in[8];
    const float* gamma    = (const float*)d_in[9];
    const float* beta     = (const float*)d_in[10];
    const float* Wp1      = (const float*)d_in[11];
    const float* bp1      = (const float*)d_in[12];
    const float* Wp2      = (const float*)d_in[13];
    const float* bp2      = (const float*)d_in[14];
    float* out = (float*)d_out;

    // workspace layout
    float* bufA = (float*)d_ws;                             // N*64 (z)
    float* bufB = bufA + (size_t)N_NODES * DF;              // N*64 (h)
    double* stats = (double*)(bufB + (size_t)N_NODES * DF); // 3*128 doubles
    float* pooled = (float*)(stats + 3 * 128);              // NGRAPH*LDIM
    float* hidden = pooled + (size_t)NGRAPH * LDIM;         // NGRAPH*LDIM
    int* gstart = (int*)(hidden + (size_t)NGRAPH * LDIM);   // NGRAPH+1
    int* deg  = gstart + NGRAPH + 1;                        // N (also cursor)
    int* off  = deg + N_NODES;                              // N+1
    int* colS = off + N_NODES + 1;                          // E
    int* blockSum = colS + N_EDGES;                         // SCAN_BLOCKS
    int* blockOff = blockSum + SCAN_BLOCKS;                 // SCAN_BLOCKS

    // ---- CSR build + graph segments (once, reused for all 3 layers) ----
    hipMemsetAsync(deg, 0, N_NODES * sizeof(int), stream);
    hist_kernel<<<(N_EDGES + 255) / 256, 256, 0, stream>>>(ei, deg);
    block_sum_kernel<<<SCAN_BLOCKS, 1024, 0, stream>>>(deg, blockSum);
    scan_partials_kernel<<<1, 128, 0, stream>>>(blockSum, blockOff);
    scan_final_kernel<<<SCAN_BLOCKS, 1024, 0, stream>>>(deg, blockOff, off);
    hipMemsetAsync(deg, 0, N_NODES * sizeof(int), stream);  // reuse as cursor
    fill_kernel<<<(N_EDGES + 255) / 256, 256, 0, stream>>>(ei, off, deg, colS);
    gstart_kernel<<<3, 256, 0, stream>>>(batch, gstart);
    hipMemsetAsync(stats, 0, 3 * 128 * sizeof(double), stream);

    const float* hin = x;
    for (int l = 0; l < 3; ++l) {
        gin_layer_kernel<<<2048, 256, 0, stream>>>(
            hin, off, colS, bufA,
            W1 + l * 4096, b1 + l * 64, W2 + l * 4096, b2 + l * 64,
            gin_eps + l, gin_bias + l * 64, stats + l * 128);

        bn_pool_kernel<<<NGRAPH, 256, 0, stream>>>(
            bufA, stats + l * 128, gamma + l * 64, beta + l * 64,
            gstart, bufB, pooled, l * 64);

        hin = bufB;
    }

    proj_kernel<<<NGRAPH, LDIM, 0, stream>>>(pooled, Wp1, bp1, hidden, 1);
    proj_kernel<<<NGRAPH, LDIM, 0, stream>>>(hidden, Wp2, bp2, out, 0);
}

// Round 6
// 416.469 us; speedup vs baseline: 3.7110x; 1.3501x over previous
//
#include <hip/hip_runtime.h>

#define N_NODES 100000
#define N_EDGES 800000
#define DF 64
#define NGRAPH 512
#define LDIM 192   // L * D
#define BN_EPS 1e-5
#define SCAN_BLOCKS 98   // ceil(100000/1024)
#define NTILES 6250      // N_NODES / 16
#define GIN_GRID 782     // ceil(NTILES / (4 waves * 2 reps))
#define NWT (GIN_GRID * 4)   // partial-stat slots (one per wave)

typedef __attribute__((ext_vector_type(8))) short bf16x8;
typedef __attribute__((ext_vector_type(4))) float f32x4;

__device__ inline short f2bf(float x) {
    union { float f; unsigned u; } v; v.f = x;
    unsigned r = v.u + 0x7fff + ((v.u >> 16) & 1);   // RNE
    return (short)(r >> 16);
}

// ---------------------------------------------------------------------------
// CSR build: histogram, 3-phase parallel exclusive scan, fill
// ---------------------------------------------------------------------------
__global__ __launch_bounds__(256) void hist_kernel(
    const int* __restrict__ ei, int* __restrict__ deg)
{
    int e = blockIdx.x * 256 + threadIdx.x;
    if (e < N_EDGES) atomicAdd(&deg[ei[e]], 1);
}

__global__ __launch_bounds__(1024) void block_sum_kernel(
    const int* __restrict__ deg, int* __restrict__ blockSum)
{
    __shared__ int ws[16];
    int b = blockIdx.x, tid = threadIdx.x;
    int idx = b * 1024 + tid;
    int v = (idx < N_NODES) ? deg[idx] : 0;
    #pragma unroll
    for (int o = 32; o > 0; o >>= 1) v += __shfl_down(v, o, 64);
    if ((tid & 63) == 0) ws[tid >> 6] = v;
    __syncthreads();
    if (tid == 0) {
        int s = 0;
        #pragma unroll
        for (int i = 0; i < 16; ++i) s += ws[i];
        blockSum[b] = s;
    }
}

__global__ __launch_bounds__(128) void scan_partials_kernel(
    const int* __restrict__ blockSum, int* __restrict__ blockOff)
{
    __shared__ int buf[SCAN_BLOCKS];
    int tid = threadIdx.x;
    if (tid < SCAN_BLOCKS) buf[tid] = blockSum[tid];
    __syncthreads();
    if (tid == 0) {
        int run = 0;
        for (int i = 0; i < SCAN_BLOCKS; ++i) {
            int v = buf[i]; buf[i] = run; run += v;
        }
    }
    __syncthreads();
    if (tid < SCAN_BLOCKS) blockOff[tid] = buf[tid];
}

__global__ __launch_bounds__(1024) void scan_final_kernel(
    const int* __restrict__ deg, const int* __restrict__ blockOff,
    int* __restrict__ off)
{
    __shared__ int buf[1024];
    int b = blockIdx.x, tid = threadIdx.x;
    int idx = b * 1024 + tid;
    int v = (idx < N_NODES) ? deg[idx] : 0;
    buf[tid] = v;
    __syncthreads();
    for (int ofs = 1; ofs < 1024; ofs <<= 1) {
        int t = (tid >= ofs) ? buf[tid - ofs] : 0;
        __syncthreads();
        buf[tid] += t;
        __syncthreads();
    }
    if (idx <= N_NODES) off[idx] = buf[tid] - v + blockOff[b];
}

__global__ __launch_bounds__(256) void fill_kernel(
    const int* __restrict__ ei, const int* __restrict__ off,
    int* __restrict__ cursor, int* __restrict__ colS)
{
    int e = blockIdx.x * 256 + threadIdx.x;
    if (e >= N_EDGES) return;
    int r = ei[e];
    int c = ei[N_EDGES + e];
    int pos = atomicAdd(&cursor[r], 1);
    colS[off[r] + pos] = c;
}

__global__ __launch_bounds__(256) void gstart_kernel(
    const int* __restrict__ batch, int* __restrict__ gstart)
{
    int g = blockIdx.x * 256 + threadIdx.x;
    if (g > NGRAPH) return;
    if (g == NGRAPH) { gstart[g] = N_NODES; return; }
    int lo = 0, hi = N_NODES;
    while (lo < hi) {
        int mid = (lo + hi) >> 1;
        if (batch[mid] < g) lo = mid + 1; else hi = mid;
    }
    gstart[g] = lo;
}

// ---------------------------------------------------------------------------
// Pack W (fp32 [64][64], z@W) into MFMA B-fragment order, bf16:
// Wpk[u][((nt*2+kt)*64 + lane)*8 + i] = bf16(W[kt*32+(lane>>4)*8+i][nt*16+(lane&15)])
// u = layer*2 + gemm
// ---------------------------------------------------------------------------
__global__ __launch_bounds__(256) void pack_w_kernel(
    const float* __restrict__ W1, const float* __restrict__ W2,
    short* __restrict__ Wpk)
{
    int u = blockIdx.x;            // 0..5
    int layer = u >> 1, gm = u & 1;
    const float* W = (gm ? W2 : W1) + layer * 4096;
    short* dst = Wpk + u * 4096;
    for (int idx = threadIdx.x; idx < 4096; idx += 256) {
        int i = idx & 7;
        int l = (idx >> 3) & 63;
        int rest = idx >> 9;       // nt*2+kt
        int kt = rest & 1, nt = rest >> 1;
        int k = kt * 32 + (l >> 4) * 8 + i;
        int n = nt * 16 + (l & 15);
        dst[idx] = f2bf(W[k * 64 + n]);
    }
}

// ---------------------------------------------------------------------------
// Fused GIN layer, MFMA version. One 16-node tile per wave, 2 reps.
// gather(fp32) -> z bf16 in wave-private LDS -> MFMA GEMM1 -> relu -> bf16 LDS
// -> MFMA GEMM2 -> bias+relu -> zout(fp32) + per-wave float BN partials.
// ---------------------------------------------------------------------------
__global__ __launch_bounds__(256) void gin_layer_kernel(
    const float* __restrict__ h,
    const int* __restrict__ off,
    const int* __restrict__ colS,
    float* __restrict__ zout,
    const short* __restrict__ Wpk,      // this layer: [2][4096]
    const float* __restrict__ b1,
    const float* __restrict__ b2,
    const float* __restrict__ gin_eps,
    const float* __restrict__ gin_bias,
    float* __restrict__ part_s,         // [64][NWT]
    float* __restrict__ part_q)
{
    __shared__ __align__(16) short Wp1s[4096];
    __shared__ __align__(16) short Wp2s[4096];
    __shared__ __align__(16) short zs[4][16 * 72];
    __shared__ __align__(16) short z1s[4][16 * 72];

    int tid = threadIdx.x;
    {   // stage packed weights (16 KB)
        const short4* s1 = (const short4*)Wpk;
        const short4* s2 = (const short4*)(Wpk + 4096);
        short4* d1 = (short4*)Wp1s;
        short4* d2 = (short4*)Wp2s;
        for (int i = tid; i < 1024; i += 256) { d1[i] = s1[i]; d2[i] = s2[i]; }
    }

    int w = tid >> 6, l = tid & 63;
    int lr = l & 15;    // A-row / B-col / D-col low index
    int lk = l >> 4;    // k-group / D-row group
    float epsf = 1.0f + gin_eps[0];
    float b1f[4], b2f[4], gbf[4];
    #pragma unroll
    for (int nt = 0; nt < 4; ++nt) {
        b1f[nt] = b1[nt * 16 + lr];
        b2f[nt] = b2[nt * 16 + lr];
        gbf[nt] = gin_bias[nt * 16 + lr];
    }
    float ssum[4] = {0, 0, 0, 0}, sq[4] = {0, 0, 0, 0};
    short* zw  = zs[w];
    short* z1w = z1s[w];
    __syncthreads();

    #pragma unroll 1
    for (int rep = 0; rep < 2; ++rep) {
        int t = (blockIdx.x * 4 + w) * 2 + rep;
        bool active = t < NTILES;
        int n0 = t * 16;

        if (active) {
            // ---- gather: lane = feature, 16 nodes, masked 8-wide ----
            for (int m = 0; m < 16; ++m) {
                int node = n0 + m;
                int s = off[node], e2 = off[node + 1];
                float acc = epsf * h[node * DF + l];
                for (int i = s; i < e2; i += 8) {
                    int cc[8]; float vv[8];
                    #pragma unroll
                    for (int j = 0; j < 8; ++j) {
                        int idx = i + j;
                        cc[j] = colS[idx < e2 ? idx : s];
                    }
                    #pragma unroll
                    for (int j = 0; j < 8; ++j) vv[j] = h[cc[j] * DF + l];
                    #pragma unroll
                    for (int j = 0; j < 8; ++j)
                        acc += (i + j < e2) ? vv[j] : 0.0f;
                }
                zw[m * 72 + l] = f2bf(acc);
            }
        }
        __syncthreads();

        // ---- GEMM1: z1 = relu(z @ W1 + b1) ----
        {
            bf16x8 a0 = *(const bf16x8*)&zw[lr * 72 + lk * 8];
            bf16x8 a1 = *(const bf16x8*)&zw[lr * 72 + 32 + lk * 8];
            #pragma unroll
            for (int nt = 0; nt < 4; ++nt) {
                f32x4 acc = {0.f, 0.f, 0.f, 0.f};
                bf16x8 bb0 = *(const bf16x8*)&Wp1s[((nt * 2 + 0) * 64 + l) * 8];
                bf16x8 bb1 = *(const bf16x8*)&Wp1s[((nt * 2 + 1) * 64 + l) * 8];
                acc = __builtin_amdgcn_mfma_f32_16x16x32_bf16(a0, bb0, acc, 0, 0, 0);
                acc = __builtin_amdgcn_mfma_f32_16x16x32_bf16(a1, bb1, acc, 0, 0, 0);
                #pragma unroll
                for (int r = 0; r < 4; ++r) {
                    float v = fmaxf(acc[r] + b1f[nt], 0.0f);
                    z1w[(lk * 4 + r) * 72 + nt * 16 + lr] = f2bf(v);
                }
            }
        }
        __syncthreads();

        // ---- GEMM2: z3 = relu(relu(z1 @ W2 + b2) + gin_bias) ----
        {
            bf16x8 a0 = *(const bf16x8*)&z1w[lr * 72 + lk * 8];
            bf16x8 a1 = *(const bf16x8*)&z1w[lr * 72 + 32 + lk * 8];
            #pragma unroll
            for (int nt = 0; nt < 4; ++nt) {
                f32x4 acc = {0.f, 0.f, 0.f, 0.f};
                bf16x8 bb0 = *(const bf16x8*)&Wp2s[((nt * 2 + 0) * 64 + l) * 8];
                bf16x8 bb1 = *(const bf16x8*)&Wp2s[((nt * 2 + 1) * 64 + l) * 8];
                acc = __builtin_amdgcn_mfma_f32_16x16x32_bf16(a0, bb0, acc, 0, 0, 0);
                acc = __builtin_amdgcn_mfma_f32_16x16x32_bf16(a1, bb1, acc, 0, 0, 0);
                if (active) {
                    #pragma unroll
                    for (int r = 0; r < 4; ++r) {
                        float v = fmaxf(fmaxf(acc[r] + b2f[nt], 0.0f) + gbf[nt], 0.0f);
                        zout[(n0 + lk * 4 + r) * DF + nt * 16 + lr] = v;
                        ssum[nt] += v;
                        sq[nt] += v * v;
                    }
                }
            }
        }
        __syncthreads();
    }

    // ---- per-wave BN partials (race-free; one slot per wave) ----
    int wt = blockIdx.x * 4 + w;
    #pragma unroll
    for (int nt = 0; nt < 4; ++nt) {
        float sv = ssum[nt], qv = sq[nt];
        sv += __shfl_xor(sv, 16, 64); sv += __shfl_xor(sv, 32, 64);
        qv += __shfl_xor(qv, 16, 64); qv += __shfl_xor(qv, 32, 64);
        if (l < 16) {
            part_s[(nt * 16 + l) * NWT + wt] = sv;
            part_q[(nt * 16 + l) * NWT + wt] = qv;
        }
    }
}

// ---------------------------------------------------------------------------
// Reduce per-wave partials -> BN scale/shift (one block per feature)
// ---------------------------------------------------------------------------
__global__ __launch_bounds__(256) void stat_reduce_kernel(
    const float* __restrict__ part_s, const float* __restrict__ part_q,
    const float* __restrict__ gamma, const float* __restrict__ beta,
    float* __restrict__ scale, float* __restrict__ shift)
{
    __shared__ double rs[4], rq[4];
    int f = blockIdx.x, tid = threadIdx.x;
    double s = 0.0, q = 0.0;
    for (int j = tid; j < NWT; j += 256) {
        s += (double)part_s[f * NWT + j];
        q += (double)part_q[f * NWT + j];
    }
    for (int o = 32; o > 0; o >>= 1) {
        s += __shfl_down(s, o, 64);
        q += __shfl_down(q, o, 64);
    }
    if ((tid & 63) == 0) { rs[tid >> 6] = s; rq[tid >> 6] = q; }
    __syncthreads();
    if (tid == 0) {
        double st = rs[0] + rs[1] + rs[2] + rs[3];
        double qt = rq[0] + rq[1] + rq[2] + rq[3];
        double mean = st / N_NODES;
        double var = qt / N_NODES - mean * mean;
        double inv = (double)gamma[f] / sqrt(var + BN_EPS);
        scale[f] = (float)inv;
        shift[f] = (float)((double)beta[f] - mean * inv);
    }
}

// ---------------------------------------------------------------------------
// Per-graph segmented BN-apply + h write + pool. One block per graph.
// ---------------------------------------------------------------------------
__global__ __launch_bounds__(256) void bn_pool_kernel(
    const float* __restrict__ z,
    const float* __restrict__ scale,
    const float* __restrict__ shift,
    const int* __restrict__ gstart,
    float* __restrict__ hout,
    float* __restrict__ pooled,
    int layerOff)
{
    __shared__ float red[4][64];
    int g = blockIdx.x;
    int tid = threadIdx.x;
    int w = tid >> 6, f = tid & 63;

    float sc = scale[f], sh = shift[f];
    int s = gstart[g], e = gstart[g + 1];
    float acc = 0.0f;
    for (int node = s + w; node < e; node += 4) {
        float v = z[node * DF + f] * sc + sh;
        hout[node * DF + f] = v;
        acc += v;
    }
    red[w][f] = acc;
    __syncthreads();
    if (w == 0)
        pooled[g * LDIM + layerOff + f] =
            red[0][f] + red[1][f] + red[2][f] + red[3][f];
}

// ---------------------------------------------------------------------------
__global__ __launch_bounds__(192) void proj_kernel(
    const float* __restrict__ in,
    const float* __restrict__ W,
    const float* __restrict__ b,
    float* __restrict__ out,
    int do_relu)
{
    __shared__ float rowS[LDIM];
    int r = blockIdx.x;
    int c = threadIdx.x;
    rowS[c] = in[r * LDIM + c];
    __syncthreads();
    float acc = b[c];
    #pragma unroll 4
    for (int k = 0; k < LDIM; ++k) acc += rowS[k] * W[k * LDIM + c];
    out[r * LDIM + c] = do_relu ? fmaxf(acc, 0.0f) : acc;
}

// ---------------------------------------------------------------------------
extern "C" void kernel_launch(void* const* d_in, const int* in_sizes, int n_in,
                              void* d_out, int out_size, void* d_ws, size_t ws_size,
                              hipStream_t stream)
{
    const float* x        = (const float*)d_in[0];
    const int*   ei       = (const int*)d_in[1];
    const int*   batch    = (const int*)d_in[2];
    const float* W1       = (const float*)d_in[3];
    const float* b1       = (const float*)d_in[4];
    const float* W2       = (const float*)d_in[5];
    const float* b2       = (const float*)d_in[6];
    const float* gin_eps  = (const float*)d_in[7];
    const float* gin_bias = (const float*)d_in[8];
    const float* gamma    = (const float*)d_in[9];
    const float* beta     = (const float*)d_in[10];
    const float* Wp1      = (const float*)d_in[11];
    const float* bp1      = (const float*)d_in[12];
    const float* Wp2      = (const float*)d_in[13];
    const float* bp2      = (const float*)d_in[14];
    float* out = (float*)d_out;

    // workspace layout (floats first, then ints, then packed shorts)
    float* bufA = (float*)d_ws;                             // N*64 (z3)
    float* bufB = bufA + (size_t)N_NODES * DF;              // N*64 (h)
    float* pooled = bufB + (size_t)N_NODES * DF;            // NGRAPH*LDIM
    float* hidden = pooled + (size_t)NGRAPH * LDIM;         // NGRAPH*LDIM
    float* scale = hidden + (size_t)NGRAPH * LDIM;          // 64
    float* shift = scale + 64;                              // 64
    float* part_s = shift + 64;                             // 64*NWT
    float* part_q = part_s + (size_t)64 * NWT;              // 64*NWT
    int* gstart = (int*)(part_q + (size_t)64 * NWT);        // NGRAPH+1
    int* deg  = gstart + NGRAPH + 1;                        // N (also cursor)
    int* off  = deg + N_NODES;                              // N+1
    int* colS = off + N_NODES + 1;                          // E
    int* blockSum = colS + N_EDGES;                         // SCAN_BLOCKS
    int* blockOff = blockSum + SCAN_BLOCKS;                 // SCAN_BLOCKS
    short* Wpk = (short*)(blockOff + SCAN_BLOCKS + 1);      // 6*4096 bf16

    // ---- CSR build + graph segments + weight pack (reused all layers) ----
    hipMemsetAsync(deg, 0, N_NODES * sizeof(int), stream);
    hist_kernel<<<(N_EDGES + 255) / 256, 256, 0, stream>>>(ei, deg);
    block_sum_kernel<<<SCAN_BLOCKS, 1024, 0, stream>>>(deg, blockSum);
    scan_partials_kernel<<<1, 128, 0, stream>>>(blockSum, blockOff);
    scan_final_kernel<<<SCAN_BLOCKS, 1024, 0, stream>>>(deg, blockOff, off);
    hipMemsetAsync(deg, 0, N_NODES * sizeof(int), stream);  // reuse as cursor
    fill_kernel<<<(N_EDGES + 255) / 256, 256, 0, stream>>>(ei, off, deg, colS);
    gstart_kernel<<<3, 256, 0, stream>>>(batch, gstart);
    pack_w_kernel<<<6, 256, 0, stream>>>(W1, W2, Wpk);

    const float* hin = x;
    for (int l = 0; l < 3; ++l) {
        gin_layer_kernel<<<GIN_GRID, 256, 0, stream>>>(
            hin, off, colS, bufA, Wpk + (size_t)l * 8192,
            b1 + l * 64, b2 + l * 64, gin_eps + l, gin_bias + l * 64,
            part_s, part_q);

        stat_reduce_kernel<<<64, 256, 0, stream>>>(
            part_s, part_q, gamma + l * 64, beta + l * 64, scale, shift);

        bn_pool_kernel<<<NGRAPH, 256, 0, stream>>>(
            bufA, scale, shift, gstart, bufB, pooled, l * 64);

        hin = bufB;
    }

    proj_kernel<<<NGRAPH, LDIM, 0, stream>>>(pooled, Wp1, bp1, hidden, 1);
    proj_kernel<<<NGRAPH, LDIM, 0, stream>>>(hidden, Wp2, bp2, out, 0);
}

// Round 7
// 407.151 us; speedup vs baseline: 3.7960x; 1.0229x over previous
//
#include <hip/hip_runtime.h>

#define N_NODES 100000
#define N_EDGES 800000
#define DF 64
#define NGRAPH 512
#define LDIM 192   // L * D
#define BN_EPS 1e-5
#define SCAN_BLOCKS 98   // ceil(100000/1024)
#define NTILES 6250      // N_NODES / 16
#define GIN_GRID 1563    // ceil(NTILES / 4 waves)
#define NWT (GIN_GRID * 4)   // partial-stat slots (one per wave)

typedef __attribute__((ext_vector_type(8))) short bf16x8;
typedef __attribute__((ext_vector_type(4))) float f32x4;

__device__ inline short f2bf(float x) {
    union { float f; unsigned u; } v; v.f = x;
    unsigned r = v.u + 0x7fff + ((v.u >> 16) & 1);   // RNE
    return (short)(r >> 16);
}

// ---------------------------------------------------------------------------
// CSR build: histogram, 3-phase parallel exclusive scan, fill
// ---------------------------------------------------------------------------
__global__ __launch_bounds__(256) void hist_kernel(
    const int* __restrict__ ei, int* __restrict__ deg)
{
    int e = blockIdx.x * 256 + threadIdx.x;
    if (e < N_EDGES) atomicAdd(&deg[ei[e]], 1);
}

__global__ __launch_bounds__(1024) void block_sum_kernel(
    const int* __restrict__ deg, int* __restrict__ blockSum)
{
    __shared__ int ws[16];
    int b = blockIdx.x, tid = threadIdx.x;
    int idx = b * 1024 + tid;
    int v = (idx < N_NODES) ? deg[idx] : 0;
    #pragma unroll
    for (int o = 32; o > 0; o >>= 1) v += __shfl_down(v, o, 64);
    if ((tid & 63) == 0) ws[tid >> 6] = v;
    __syncthreads();
    if (tid == 0) {
        int s = 0;
        #pragma unroll
        for (int i = 0; i < 16; ++i) s += ws[i];
        blockSum[b] = s;
    }
}

__global__ __launch_bounds__(128) void scan_partials_kernel(
    const int* __restrict__ blockSum, int* __restrict__ blockOff)
{
    __shared__ int buf[SCAN_BLOCKS];
    int tid = threadIdx.x;
    if (tid < SCAN_BLOCKS) buf[tid] = blockSum[tid];
    __syncthreads();
    if (tid == 0) {
        int run = 0;
        for (int i = 0; i < SCAN_BLOCKS; ++i) {
            int v = buf[i]; buf[i] = run; run += v;
        }
    }
    __syncthreads();
    if (tid < SCAN_BLOCKS) blockOff[tid] = buf[tid];
}

__global__ __launch_bounds__(1024) void scan_final_kernel(
    const int* __restrict__ deg, const int* __restrict__ blockOff,
    int* __restrict__ off)
{
    __shared__ int buf[1024];
    int b = blockIdx.x, tid = threadIdx.x;
    int idx = b * 1024 + tid;
    int v = (idx < N_NODES) ? deg[idx] : 0;
    buf[tid] = v;
    __syncthreads();
    for (int ofs = 1; ofs < 1024; ofs <<= 1) {
        int t = (tid >= ofs) ? buf[tid - ofs] : 0;
        __syncthreads();
        buf[tid] += t;
        __syncthreads();
    }
    if (idx <= N_NODES) off[idx] = buf[tid] - v + blockOff[b];
}

__global__ __launch_bounds__(256) void fill_kernel(
    const int* __restrict__ ei, const int* __restrict__ off,
    int* __restrict__ cursor, int* __restrict__ colS)
{
    int e = blockIdx.x * 256 + threadIdx.x;
    if (e >= N_EDGES) return;
    int r = ei[e];
    int c = ei[N_EDGES + e];
    int pos = atomicAdd(&cursor[r], 1);
    colS[off[r] + pos] = c;
}

__global__ __launch_bounds__(256) void gstart_kernel(
    const int* __restrict__ batch, int* __restrict__ gstart)
{
    int g = blockIdx.x * 256 + threadIdx.x;
    if (g > NGRAPH) return;
    if (g == NGRAPH) { gstart[g] = N_NODES; return; }
    int lo = 0, hi = N_NODES;
    while (lo < hi) {
        int mid = (lo + hi) >> 1;
        if (batch[mid] < g) lo = mid + 1; else hi = mid;
    }
    gstart[g] = lo;
}

__global__ void init_id_kernel(float* __restrict__ idsc, float* __restrict__ idsh)
{
    int f = threadIdx.x;
    idsc[f] = 1.0f;
    idsh[f] = 0.0f;
}

// ---------------------------------------------------------------------------
// Pack W (fp32 [64][64], z@W) into MFMA B-fragment order, bf16.
// ---------------------------------------------------------------------------
__global__ __launch_bounds__(256) void pack_w_kernel(
    const float* __restrict__ W1, const float* __restrict__ W2,
    short* __restrict__ Wpk)
{
    int u = blockIdx.x;            // 0..5 = layer*2 + gemm
    int layer = u >> 1, gm = u & 1;
    const float* W = (gm ? W2 : W1) + layer * 4096;
    short* dst = Wpk + u * 4096;
    for (int idx = threadIdx.x; idx < 4096; idx += 256) {
        int i = idx & 7;
        int l = (idx >> 3) & 63;
        int rest = idx >> 9;       // nt*2+kt
        int kt = rest & 1, nt = rest >> 1;
        int k = kt * 32 + (l >> 4) * 8 + i;
        int n = nt * 16 + (l & 15);
        dst[idx] = f2bf(W[k * 64 + n]);
    }
}

// ---------------------------------------------------------------------------
// Fused GIN layer (MFMA). One 16-node tile per wave. BN of the PREVIOUS
// layer is folded in algebraically:
//   z = sc*((1+eps)*zp_n + sum_c zp_c) + (1+eps+deg)*sh
// No barriers in the tile body (all LDS rows are wave-private). z/z1 share
// one LDS buffer. Writes z3 (pre-BN) + per-wave float BN partials.
// ---------------------------------------------------------------------------
__global__ __launch_bounds__(256) void gin_layer_kernel(
    const float* __restrict__ zp,       // prev z3 (or x for layer 0)
    const float* __restrict__ sc_in,    // prev BN scale (or 1.0)
    const float* __restrict__ sh_in,    // prev BN shift (or 0.0)
    const int* __restrict__ off,
    const int* __restrict__ colS,
    float* __restrict__ zout,
    const short* __restrict__ Wpk,      // this layer: [2][4096]
    const float* __restrict__ b1,
    const float* __restrict__ b2,
    const float* __restrict__ gin_eps,
    const float* __restrict__ gin_bias,
    float* __restrict__ part_s,         // [64][NWT]
    float* __restrict__ part_q)
{
    __shared__ __align__(16) short Wp1s[4096];
    __shared__ __align__(16) short Wp2s[4096];
    __shared__ __align__(16) short zs[4][16 * 72];   // z, then z1 (wave-private)

    int tid = threadIdx.x;
    {   // stage packed weights (16 KB), once per block
        const short4* s1 = (const short4*)Wpk;
        const short4* s2 = (const short4*)(Wpk + 4096);
        short4* d1 = (short4*)Wp1s;
        short4* d2 = (short4*)Wp2s;
        for (int i = tid; i < 1024; i += 256) { d1[i] = s1[i]; d2[i] = s2[i]; }
    }

    int w = tid >> 6, l = tid & 63;
    int lr = l & 15;    // A-row / B-col / D-col low index
    int lk = l >> 4;    // k-group / D-row group
    float epsf = 1.0f + gin_eps[0];
    float scf = sc_in[l], shf = sh_in[l];
    float b1f[4], b2f[4], gbf[4];
    #pragma unroll
    for (int nt = 0; nt < 4; ++nt) {
        b1f[nt] = b1[nt * 16 + lr];
        b2f[nt] = b2[nt * 16 + lr];
        gbf[nt] = gin_bias[nt * 16 + lr];
    }
    float ssum[4] = {0, 0, 0, 0}, sq[4] = {0, 0, 0, 0};
    short* zw = zs[w];
    __syncthreads();

    int t = blockIdx.x * 4 + w;
    bool active = t < NTILES;
    int n0 = t * 16;

    if (active) {
        // ---- gather (lane = feature), masked 8-wide, BN folded ----
        for (int m = 0; m < 16; ++m) {
            int node = n0 + m;
            int s = off[node], e2 = off[node + 1];
            float acc = epsf * zp[node * DF + l];
            for (int i = s; i < e2; i += 8) {
                int cc[8]; float vv[8];
                #pragma unroll
                for (int j = 0; j < 8; ++j) {
                    int idx = i + j;
                    cc[j] = colS[idx < e2 ? idx : s];
                }
                #pragma unroll
                for (int j = 0; j < 8; ++j) vv[j] = zp[cc[j] * DF + l];
                #pragma unroll
                for (int j = 0; j < 8; ++j)
                    acc += (i + j < e2) ? vv[j] : 0.0f;
            }
            float zf = scf * acc + (epsf + (float)(e2 - s)) * shf;
            zw[m * 72 + l] = f2bf(zf);
        }

        // ---- GEMM1: z1 = relu(z @ W1 + b1)  (z1 overwrites z rows) ----
        {
            bf16x8 a0 = *(const bf16x8*)&zw[lr * 72 + lk * 8];
            bf16x8 a1 = *(const bf16x8*)&zw[lr * 72 + 32 + lk * 8];
            #pragma unroll
            for (int nt = 0; nt < 4; ++nt) {
                f32x4 acc = {0.f, 0.f, 0.f, 0.f};
                bf16x8 bb0 = *(const bf16x8*)&Wp1s[((nt * 2 + 0) * 64 + l) * 8];
                bf16x8 bb1 = *(const bf16x8*)&Wp1s[((nt * 2 + 1) * 64 + l) * 8];
                acc = __builtin_amdgcn_mfma_f32_16x16x32_bf16(a0, bb0, acc, 0, 0, 0);
                acc = __builtin_amdgcn_mfma_f32_16x16x32_bf16(a1, bb1, acc, 0, 0, 0);
                #pragma unroll
                for (int r = 0; r < 4; ++r) {
                    float v = fmaxf(acc[r] + b1f[nt], 0.0f);
                    zw[(lk * 4 + r) * 72 + nt * 16 + lr] = f2bf(v);
                }
            }
        }

        // ---- GEMM2: z3 = relu(relu(z1 @ W2 + b2) + gin_bias) ----
        {
            bf16x8 a0 = *(const bf16x8*)&zw[lr * 72 + lk * 8];
            bf16x8 a1 = *(const bf16x8*)&zw[lr * 72 + 32 + lk * 8];
            #pragma unroll
            for (int nt = 0; nt < 4; ++nt) {
                f32x4 acc = {0.f, 0.f, 0.f, 0.f};
                bf16x8 bb0 = *(const bf16x8*)&Wp2s[((nt * 2 + 0) * 64 + l) * 8];
                bf16x8 bb1 = *(const bf16x8*)&Wp2s[((nt * 2 + 1) * 64 + l) * 8];
                acc = __builtin_amdgcn_mfma_f32_16x16x32_bf16(a0, bb0, acc, 0, 0, 0);
                acc = __builtin_amdgcn_mfma_f32_16x16x32_bf16(a1, bb1, acc, 0, 0, 0);
                #pragma unroll
                for (int r = 0; r < 4; ++r) {
                    float v = fmaxf(fmaxf(acc[r] + b2f[nt], 0.0f) + gbf[nt], 0.0f);
                    zout[(n0 + lk * 4 + r) * DF + nt * 16 + lr] = v;
                    ssum[nt] += v;
                    sq[nt] += v * v;
                }
            }
        }
    }

    // ---- per-wave BN partials (all waves write; zeros if inactive) ----
    #pragma unroll
    for (int nt = 0; nt < 4; ++nt) {
        float sv = ssum[nt], qv = sq[nt];
        sv += __shfl_xor(sv, 16, 64); sv += __shfl_xor(sv, 32, 64);
        qv += __shfl_xor(qv, 16, 64); qv += __shfl_xor(qv, 32, 64);
        if (l < 16) {
            part_s[(nt * 16 + l) * NWT + t] = sv;
            part_q[(nt * 16 + l) * NWT + t] = qv;
        }
    }
}

// ---------------------------------------------------------------------------
// Reduce per-wave partials -> BN scale/shift (one block per feature)
// ---------------------------------------------------------------------------
__global__ __launch_bounds__(256) void stat_reduce_kernel(
    const float* __restrict__ part_s, const float* __restrict__ part_q,
    const float* __restrict__ gamma, const float* __restrict__ beta,
    float* __restrict__ scale, float* __restrict__ shift)
{
    __shared__ double rs[4], rq[4];
    int f = blockIdx.x, tid = threadIdx.x;
    double s = 0.0, q = 0.0;
    for (int j = tid; j < NWT; j += 256) {
        s += (double)part_s[f * NWT + j];
        q += (double)part_q[f * NWT + j];
    }
    for (int o = 32; o > 0; o >>= 1) {
        s += __shfl_down(s, o, 64);
        q += __shfl_down(q, o, 64);
    }
    if ((tid & 63) == 0) { rs[tid >> 6] = s; rq[tid >> 6] = q; }
    __syncthreads();
    if (tid == 0) {
        double st = rs[0] + rs[1] + rs[2] + rs[3];
        double qt = rq[0] + rq[1] + rq[2] + rq[3];
        double mean = st / N_NODES;
        double var = qt / N_NODES - mean * mean;
        double inv = (double)gamma[f] / sqrt(var + BN_EPS);
        scale[f] = (float)inv;
        shift[f] = (float)((double)beta[f] - mean * inv);
    }
}

// ---------------------------------------------------------------------------
// Pool-only: pooled[g] = sc * sum_{nodes in g} z3 + cnt(g) * sh
// ---------------------------------------------------------------------------
__global__ __launch_bounds__(256) void pool_kernel(
    const float* __restrict__ z,
    const float* __restrict__ scale,
    const float* __restrict__ shift,
    const int* __restrict__ gstart,
    float* __restrict__ pooled,
    int layerOff)
{
    __shared__ float red[4][64];
    int g = blockIdx.x;
    int tid = threadIdx.x;
    int w = tid >> 6, f = tid & 63;

    int s = gstart[g], e = gstart[g + 1];
    float acc = 0.0f;
    for (int node = s + w; node < e; node += 4)
        acc += z[node * DF + f];
    red[w][f] = acc;
    __syncthreads();
    if (w == 0)
        pooled[g * LDIM + layerOff + f] =
            scale[f] * (red[0][f] + red[1][f] + red[2][f] + red[3][f])
            + (float)(e - s) * shift[f];
}

// ---------------------------------------------------------------------------
__global__ __launch_bounds__(192) void proj_kernel(
    const float* __restrict__ in,
    const float* __restrict__ W,
    const float* __restrict__ b,
    float* __restrict__ out,
    int do_relu)
{
    __shared__ float rowS[LDIM];
    int r = blockIdx.x;
    int c = threadIdx.x;
    rowS[c] = in[r * LDIM + c];
    __syncthreads();
    float acc = b[c];
    #pragma unroll 4
    for (int k = 0; k < LDIM; ++k) acc += rowS[k] * W[k * LDIM + c];
    out[r * LDIM + c] = do_relu ? fmaxf(acc, 0.0f) : acc;
}

// ---------------------------------------------------------------------------
extern "C" void kernel_launch(void* const* d_in, const int* in_sizes, int n_in,
                              void* d_out, int out_size, void* d_ws, size_t ws_size,
                              hipStream_t stream)
{
    const float* x        = (const float*)d_in[0];
    const int*   ei       = (const int*)d_in[1];
    const int*   batch    = (const int*)d_in[2];
    const float* W1       = (const float*)d_in[3];
    const float* b1       = (const float*)d_in[4];
    const float* W2       = (const float*)d_in[5];
    const float* b2       = (const float*)d_in[6];
    const float* gin_eps  = (const float*)d_in[7];
    const float* gin_bias = (const float*)d_in[8];
    const float* gamma    = (const float*)d_in[9];
    const float* beta     = (const float*)d_in[10];
    const float* Wp1      = (const float*)d_in[11];
    const float* bp1      = (const float*)d_in[12];
    const float* Wp2      = (const float*)d_in[13];
    const float* bp2      = (const float*)d_in[14];
    float* out = (float*)d_out;

    // workspace layout
    float* bufA = (float*)d_ws;                             // N*64 (z3 even layers)
    float* bufB = bufA + (size_t)N_NODES * DF;              // N*64 (z3 odd layers)
    float* pooled = bufB + (size_t)N_NODES * DF;            // NGRAPH*LDIM
    float* hidden = pooled + (size_t)NGRAPH * LDIM;         // NGRAPH*LDIM
    float* scale = hidden + (size_t)NGRAPH * LDIM;          // 64
    float* shift = scale + 64;                              // 64
    float* idsc = shift + 64;                               // 64 (1.0)
    float* idsh = idsc + 64;                                // 64 (0.0)
    float* part_s = idsh + 64;                              // 64*NWT
    float* part_q = part_s + (size_t)64 * NWT;              // 64*NWT
    int* gstart = (int*)(part_q + (size_t)64 * NWT);        // NGRAPH+1
    int* deg  = gstart + NGRAPH + 1;                        // N (also cursor)
    int* off  = deg + N_NODES;                              // N+1
    int* colS = off + N_NODES + 1;                          // E
    int* blockSum = colS + N_EDGES;                         // SCAN_BLOCKS
    int* blockOff = blockSum + SCAN_BLOCKS;                 // SCAN_BLOCKS
    short* Wpk = (short*)(blockOff + SCAN_BLOCKS + 1);      // 6*4096 bf16

    // ---- CSR build + graph segments + weight pack (reused all layers) ----
    hipMemsetAsync(deg, 0, N_NODES * sizeof(int), stream);
    hist_kernel<<<(N_EDGES + 255) / 256, 256, 0, stream>>>(ei, deg);
    block_sum_kernel<<<SCAN_BLOCKS, 1024, 0, stream>>>(deg, blockSum);
    scan_partials_kernel<<<1, 128, 0, stream>>>(blockSum, blockOff);
    scan_final_kernel<<<SCAN_BLOCKS, 1024, 0, stream>>>(deg, blockOff, off);
    hipMemsetAsync(deg, 0, N_NODES * sizeof(int), stream);  // reuse as cursor
    fill_kernel<<<(N_EDGES + 255) / 256, 256, 0, stream>>>(ei, off, deg, colS);
    gstart_kernel<<<3, 256, 0, stream>>>(batch, gstart);
    init_id_kernel<<<1, 64, 0, stream>>>(idsc, idsh);
    pack_w_kernel<<<6, 256, 0, stream>>>(W1, W2, Wpk);

    const float* zprev = x;
    const float* sc_in = idsc;
    const float* sh_in = idsh;
    float* zbuf[2] = {bufA, bufB};
    for (int l = 0; l < 3; ++l) {
        float* zcur = zbuf[l & 1];
        gin_layer_kernel<<<GIN_GRID, 256, 0, stream>>>(
            zprev, sc_in, sh_in, off, colS, zcur,
            Wpk + (size_t)l * 8192,
            b1 + l * 64, b2 + l * 64, gin_eps + l, gin_bias + l * 64,
            part_s, part_q);

        stat_reduce_kernel<<<64, 256, 0, stream>>>(
            part_s, part_q, gamma + l * 64, beta + l * 64, scale + 0, shift + 0);

        pool_kernel<<<NGRAPH, 256, 0, stream>>>(
            zcur, scale, shift, gstart, pooled, l * 64);

        zprev = zcur;
        sc_in = scale;
        sh_in = shift;
    }

    proj_kernel<<<NGRAPH, LDIM, 0, stream>>>(pooled, Wp1, bp1, hidden, 1);
    proj_kernel<<<NGRAPH, LDIM, 0, stream>>>(hidden, Wp2, bp2, out, 0);
}

// Round 8
// 367.706 us; speedup vs baseline: 4.2032x; 1.1073x over previous
//
#include <hip/hip_runtime.h>

#define N_NODES 100000
#define N_EDGES 800000
#define DF 64
#define NGRAPH 512
#define LDIM 192   // L * D
#define BN_EPS 1e-5
#define SCAN_BLOCKS 98   // ceil(100000/1024)
#define NTILES 6250      // N_NODES / 16
#define GIN_GRID 1563    // ceil(NTILES / 4 waves)
#define NWT (GIN_GRID * 4)   // partial-stat slots (one per wave)
#define COLS_CAP 2600000     // sum of padded degrees < 2.4M

typedef __attribute__((ext_vector_type(8))) short bf16x8;
typedef __attribute__((ext_vector_type(4))) float f32x4;

__device__ inline short f2bf(float x) {
    union { float f; unsigned u; } v; v.f = x;
    unsigned r = v.u + 0x7fff + ((v.u >> 16) & 1);   // RNE
    return (short)(r >> 16);
}

__device__ inline int pdeg_of(int d) {   // pad to multiple of 16, min 16
    int p = (d + 15) & ~15;
    return p < 16 ? 16 : p;
}

// ---------------------------------------------------------------------------
// CSR build: histogram, 3-phase parallel exclusive scan over PADDED degrees
// ---------------------------------------------------------------------------
__global__ __launch_bounds__(256) void hist_kernel(
    const int* __restrict__ ei, int* __restrict__ deg)
{
    int e = blockIdx.x * 256 + threadIdx.x;
    if (e < N_EDGES) atomicAdd(&deg[ei[e]], 1);
}

__global__ __launch_bounds__(1024) void block_sum_kernel(
    const int* __restrict__ deg, int* __restrict__ blockSum)
{
    __shared__ int ws[16];
    int b = blockIdx.x, tid = threadIdx.x;
    int idx = b * 1024 + tid;
    int v = (idx < N_NODES) ? pdeg_of(deg[idx]) : 0;
    #pragma unroll
    for (int o = 32; o > 0; o >>= 1) v += __shfl_down(v, o, 64);
    if ((tid & 63) == 0) ws[tid >> 6] = v;
    __syncthreads();
    if (tid == 0) {
        int s = 0;
        #pragma unroll
        for (int i = 0; i < 16; ++i) s += ws[i];
        blockSum[b] = s;
    }
}

__global__ __launch_bounds__(128) void scan_partials_kernel(
    const int* __restrict__ blockSum, int* __restrict__ blockOff)
{
    __shared__ int buf[SCAN_BLOCKS];
    int tid = threadIdx.x;
    if (tid < SCAN_BLOCKS) buf[tid] = blockSum[tid];
    __syncthreads();
    if (tid == 0) {
        int run = 0;
        for (int i = 0; i < SCAN_BLOCKS; ++i) {
            int v = buf[i]; buf[i] = run; run += v;
        }
    }
    __syncthreads();
    if (tid < SCAN_BLOCKS) blockOff[tid] = buf[tid];
}

__global__ __launch_bounds__(1024) void scan_final_kernel(
    const int* __restrict__ deg, const int* __restrict__ blockOff,
    int* __restrict__ off)
{
    __shared__ int buf[1024];
    int b = blockIdx.x, tid = threadIdx.x;
    int idx = b * 1024 + tid;
    int v = (idx < N_NODES) ? pdeg_of(deg[idx]) : 0;
    buf[tid] = v;
    __syncthreads();
    for (int ofs = 1; ofs < 1024; ofs <<= 1) {
        int t = (tid >= ofs) ? buf[tid - ofs] : 0;
        __syncthreads();
        buf[tid] += t;
        __syncthreads();
    }
    if (idx <= N_NODES) off[idx] = buf[tid] - v + blockOff[b];
}

// real edges: colS[off[r] + pos] = c * DF (element offset)
__global__ __launch_bounds__(256) void fill_kernel(
    const int* __restrict__ ei, const int* __restrict__ off,
    int* __restrict__ cursor, int* __restrict__ colS)
{
    int e = blockIdx.x * 256 + threadIdx.x;
    if (e >= N_EDGES) return;
    int r = ei[e];
    int c = ei[N_EDGES + e];
    int pos = atomicAdd(&cursor[r], 1);
    colS[off[r] + pos] = c * DF;
}

// pad slots point at the node's OWN row (corrected algebraically in gather)
__global__ __launch_bounds__(256) void pad_kernel(
    const int* __restrict__ off, const int* __restrict__ deg,
    int* __restrict__ colS)
{
    int v = blockIdx.x * 256 + threadIdx.x;
    if (v >= N_NODES) return;
    int s = off[v] + deg[v], e = off[v + 1];
    int sent = v * DF;
    for (int i = s; i < e; ++i) colS[i] = sent;
}

__global__ __launch_bounds__(256) void gstart_kernel(
    const int* __restrict__ batch, int* __restrict__ gstart)
{
    int g = blockIdx.x * 256 + threadIdx.x;
    if (g > NGRAPH) return;
    if (g == NGRAPH) { gstart[g] = N_NODES; return; }
    int lo = 0, hi = N_NODES;
    while (lo < hi) {
        int mid = (lo + hi) >> 1;
        if (batch[mid] < g) lo = mid + 1; else hi = mid;
    }
    gstart[g] = lo;
}

__global__ void init_id_kernel(float* __restrict__ idsc, float* __restrict__ idsh)
{
    int f = threadIdx.x;
    idsc[f] = 1.0f;
    idsh[f] = 0.0f;
}

// ---------------------------------------------------------------------------
// Pack W (fp32 [64][64], z@W) into MFMA B-fragment order, bf16.
// ---------------------------------------------------------------------------
__global__ __launch_bounds__(256) void pack_w_kernel(
    const float* __restrict__ W1, const float* __restrict__ W2,
    short* __restrict__ Wpk)
{
    int u = blockIdx.x;            // 0..5 = layer*2 + gemm
    int layer = u >> 1, gm = u & 1;
    const float* W = (gm ? W2 : W1) + layer * 4096;
    short* dst = Wpk + u * 4096;
    for (int idx = threadIdx.x; idx < 4096; idx += 256) {
        int i = idx & 7;
        int l = (idx >> 3) & 63;
        int rest = idx >> 9;       // nt*2+kt
        int kt = rest & 1, nt = rest >> 1;
        int k = kt * 32 + (l >> 4) * 8 + i;
        int n = nt * 16 + (l & 15);
        dst[idx] = f2bf(W[k * 64 + n]);
    }
}

// ---------------------------------------------------------------------------
// Fused GIN layer (MFMA). One 16-node tile per wave. Branchless padded
// gather with scalar (SALU) addressing; prev-layer BN folded in:
//   z = sc*((1+eps-npad)*zp_n + sum_all) + (1+eps+deg)*sh
// ---------------------------------------------------------------------------
__global__ __launch_bounds__(256) void gin_layer_kernel(
    const float* __restrict__ zp,       // prev z3 (or x for layer 0)
    const float* __restrict__ sc_in,    // prev BN scale (or 1.0)
    const float* __restrict__ sh_in,    // prev BN shift (or 0.0)
    const int* __restrict__ off,        // padded CSR offsets
    const int* __restrict__ deg,        // real degrees
    const int* __restrict__ colS,       // element offsets (c*64), padded
    float* __restrict__ zout,
    const short* __restrict__ Wpk,      // this layer: [2][4096]
    const float* __restrict__ b1,
    const float* __restrict__ b2,
    const float* __restrict__ gin_eps,
    const float* __restrict__ gin_bias,
    float* __restrict__ part_s,         // [64][NWT]
    float* __restrict__ part_q)
{
    __shared__ __align__(16) short Wp1s[4096];
    __shared__ __align__(16) short Wp2s[4096];
    __shared__ __align__(16) short zs[4][16 * 72];   // z, then z1 (wave-private)

    int tid = threadIdx.x;
    {   // stage packed weights (16 KB), once per block
        const short4* s1 = (const short4*)Wpk;
        const short4* s2 = (const short4*)(Wpk + 4096);
        short4* d1 = (short4*)Wp1s;
        short4* d2 = (short4*)Wp2s;
        for (int i = tid; i < 1024; i += 256) { d1[i] = s1[i]; d2[i] = s2[i]; }
    }

    int w = tid >> 6, l = tid & 63;
    int lr = l & 15;    // A-row / B-col / D-col low index
    int lk = l >> 4;    // k-group / D-row group
    float epsf = 1.0f + gin_eps[0];
    float scf = sc_in[l], shf = sh_in[l];
    float b1f[4], b2f[4], gbf[4];
    #pragma unroll
    for (int nt = 0; nt < 4; ++nt) {
        b1f[nt] = b1[nt * 16 + lr];
        b2f[nt] = b2[nt * 16 + lr];
        gbf[nt] = gin_bias[nt * 16 + lr];
    }
    float ssum[4] = {0, 0, 0, 0}, sq[4] = {0, 0, 0, 0};
    short* zw = zs[w];
    __syncthreads();

    int t = blockIdx.x * 4 + w;
    bool active = t < NTILES;
    int n0 = t * 16;

    if (active) {
        // ---- gather: 2 nodes in flight (32 loads), branchless first batch --
        #pragma unroll 1
        for (int mp = 0; mp < 8; ++mp) {
            int nodeA = n0 + (mp << 1);
            int nodeB = nodeA + 1;
            int sA = __builtin_amdgcn_readfirstlane(off[nodeA]);
            int eA = __builtin_amdgcn_readfirstlane(off[nodeA + 1]);
            int dA = __builtin_amdgcn_readfirstlane(deg[nodeA]);
            int sB = __builtin_amdgcn_readfirstlane(off[nodeB]);
            int eB = __builtin_amdgcn_readfirstlane(off[nodeB + 1]);
            int dB = __builtin_amdgcn_readfirstlane(deg[nodeB]);
            float hnA = zp[nodeA * DF + l];
            float hnB = zp[nodeB * DF + l];
            float vA[16], vB[16];
            #pragma unroll
            for (int j = 0; j < 16; ++j) {
                int co = __builtin_amdgcn_readfirstlane(colS[sA + j]);
                vA[j] = zp[co + l];
            }
            #pragma unroll
            for (int j = 0; j < 16; ++j) {
                int co = __builtin_amdgcn_readfirstlane(colS[sB + j]);
                vB[j] = zp[co + l];
            }
            float aA0 = (vA[0] + vA[1]) + (vA[2] + vA[3]);
            float aA1 = (vA[4] + vA[5]) + (vA[6] + vA[7]);
            float aA2 = (vA[8] + vA[9]) + (vA[10] + vA[11]);
            float aA3 = (vA[12] + vA[13]) + (vA[14] + vA[15]);
            float accA = (aA0 + aA1) + (aA2 + aA3);
            float aB0 = (vB[0] + vB[1]) + (vB[2] + vB[3]);
            float aB1 = (vB[4] + vB[5]) + (vB[6] + vB[7]);
            float aB2 = (vB[8] + vB[9]) + (vB[10] + vB[11]);
            float aB3 = (vB[12] + vB[13]) + (vB[14] + vB[15]);
            float accB = (aB0 + aB1) + (aB2 + aB3);
            // rare remainder (deg > 16): ~0.4% of nodes
            for (int i = sA + 16; i < eA; i += 16) {
                #pragma unroll
                for (int j = 0; j < 16; ++j) {
                    int co = __builtin_amdgcn_readfirstlane(colS[i + j]);
                    accA += zp[co + l];
                }
            }
            for (int i = sB + 16; i < eB; i += 16) {
                #pragma unroll
                for (int j = 0; j < 16; ++j) {
                    int co = __builtin_amdgcn_readfirstlane(colS[i + j]);
                    accB += zp[co + l];
                }
            }
            float npA = (float)(eA - sA - dA);
            float npB = (float)(eB - sB - dB);
            float zfA = scf * ((epsf - npA) * hnA + accA) + (epsf + (float)dA) * shf;
            float zfB = scf * ((epsf - npB) * hnB + accB) + (epsf + (float)dB) * shf;
            zw[(mp * 2) * 72 + l] = f2bf(zfA);
            zw[(mp * 2 + 1) * 72 + l] = f2bf(zfB);
        }

        // ---- GEMM1: z1 = relu(z @ W1 + b1)  (z1 overwrites z rows) ----
        {
            bf16x8 a0 = *(const bf16x8*)&zw[lr * 72 + lk * 8];
            bf16x8 a1 = *(const bf16x8*)&zw[lr * 72 + 32 + lk * 8];
            #pragma unroll
            for (int nt = 0; nt < 4; ++nt) {
                f32x4 acc = {0.f, 0.f, 0.f, 0.f};
                bf16x8 bb0 = *(const bf16x8*)&Wp1s[((nt * 2 + 0) * 64 + l) * 8];
                bf16x8 bb1 = *(const bf16x8*)&Wp1s[((nt * 2 + 1) * 64 + l) * 8];
                acc = __builtin_amdgcn_mfma_f32_16x16x32_bf16(a0, bb0, acc, 0, 0, 0);
                acc = __builtin_amdgcn_mfma_f32_16x16x32_bf16(a1, bb1, acc, 0, 0, 0);
                #pragma unroll
                for (int r = 0; r < 4; ++r) {
                    float v = fmaxf(acc[r] + b1f[nt], 0.0f);
                    zw[(lk * 4 + r) * 72 + nt * 16 + lr] = f2bf(v);
                }
            }
        }

        // ---- GEMM2: z3 = relu(relu(z1 @ W2 + b2) + gin_bias) ----
        {
            bf16x8 a0 = *(const bf16x8*)&zw[lr * 72 + lk * 8];
            bf16x8 a1 = *(const bf16x8*)&zw[lr * 72 + 32 + lk * 8];
            #pragma unroll
            for (int nt = 0; nt < 4; ++nt) {
                f32x4 acc = {0.f, 0.f, 0.f, 0.f};
                bf16x8 bb0 = *(const bf16x8*)&Wp2s[((nt * 2 + 0) * 64 + l) * 8];
                bf16x8 bb1 = *(const bf16x8*)&Wp2s[((nt * 2 + 1) * 64 + l) * 8];
                acc = __builtin_amdgcn_mfma_f32_16x16x32_bf16(a0, bb0, acc, 0, 0, 0);
                acc = __builtin_amdgcn_mfma_f32_16x16x32_bf16(a1, bb1, acc, 0, 0, 0);
                #pragma unroll
                for (int r = 0; r < 4; ++r) {
                    float v = fmaxf(fmaxf(acc[r] + b2f[nt], 0.0f) + gbf[nt], 0.0f);
                    zout[(n0 + lk * 4 + r) * DF + nt * 16 + lr] = v;
                    ssum[nt] += v;
                    sq[nt] += v * v;
                }
            }
        }
    }

    // ---- per-wave BN partials (all waves write; zeros if inactive) ----
    #pragma unroll
    for (int nt = 0; nt < 4; ++nt) {
        float sv = ssum[nt], qv = sq[nt];
        sv += __shfl_xor(sv, 16, 64); sv += __shfl_xor(sv, 32, 64);
        qv += __shfl_xor(qv, 16, 64); qv += __shfl_xor(qv, 32, 64);
        if (l < 16) {
            part_s[(nt * 16 + l) * NWT + t] = sv;
            part_q[(nt * 16 + l) * NWT + t] = qv;
        }
    }
}

// ---------------------------------------------------------------------------
// Reduce per-wave partials -> BN scale/shift (one block per feature)
// ---------------------------------------------------------------------------
__global__ __launch_bounds__(256) void stat_reduce_kernel(
    const float* __restrict__ part_s, const float* __restrict__ part_q,
    const float* __restrict__ gamma, const float* __restrict__ beta,
    float* __restrict__ scale, float* __restrict__ shift)
{
    __shared__ double rs[4], rq[4];
    int f = blockIdx.x, tid = threadIdx.x;
    double s = 0.0, q = 0.0;
    for (int j = tid; j < NWT; j += 256) {
        s += (double)part_s[f * NWT + j];
        q += (double)part_q[f * NWT + j];
    }
    for (int o = 32; o > 0; o >>= 1) {
        s += __shfl_down(s, o, 64);
        q += __shfl_down(q, o, 64);
    }
    if ((tid & 63) == 0) { rs[tid >> 6] = s; rq[tid >> 6] = q; }
    __syncthreads();
    if (tid == 0) {
        double st = rs[0] + rs[1] + rs[2] + rs[3];
        double qt = rq[0] + rq[1] + rq[2] + rq[3];
        double mean = st / N_NODES;
        double var = qt / N_NODES - mean * mean;
        double inv = (double)gamma[f] / sqrt(var + BN_EPS);
        scale[f] = (float)inv;
        shift[f] = (float)((double)beta[f] - mean * inv);
    }
}

// ---------------------------------------------------------------------------
// Pool-only: pooled[g] = sc * sum_{nodes in g} z3 + cnt(g) * sh
// ---------------------------------------------------------------------------
__global__ __launch_bounds__(256) void pool_kernel(
    const float* __restrict__ z,
    const float* __restrict__ scale,
    const float* __restrict__ shift,
    const int* __restrict__ gstart,
    float* __restrict__ pooled,
    int layerOff)
{
    __shared__ float red[4][64];
    int g = blockIdx.x;
    int tid = threadIdx.x;
    int w = tid >> 6, f = tid & 63;

    int s = gstart[g], e = gstart[g + 1];
    float acc = 0.0f;
    for (int node = s + w; node < e; node += 4)
        acc += z[node * DF + f];
    red[w][f] = acc;
    __syncthreads();
    if (w == 0)
        pooled[g * LDIM + layerOff + f] =
            scale[f] * (red[0][f] + red[1][f] + red[2][f] + red[3][f])
            + (float)(e - s) * shift[f];
}

// ---------------------------------------------------------------------------
__global__ __launch_bounds__(192) void proj_kernel(
    const float* __restrict__ in,
    const float* __restrict__ W,
    const float* __restrict__ b,
    float* __restrict__ out,
    int do_relu)
{
    __shared__ float rowS[LDIM];
    int r = blockIdx.x;
    int c = threadIdx.x;
    rowS[c] = in[r * LDIM + c];
    __syncthreads();
    float acc = b[c];
    #pragma unroll 4
    for (int k = 0; k < LDIM; ++k) acc += rowS[k] * W[k * LDIM + c];
    out[r * LDIM + c] = do_relu ? fmaxf(acc, 0.0f) : acc;
}

// ---------------------------------------------------------------------------
extern "C" void kernel_launch(void* const* d_in, const int* in_sizes, int n_in,
                              void* d_out, int out_size, void* d_ws, size_t ws_size,
                              hipStream_t stream)
{
    const float* x        = (const float*)d_in[0];
    const int*   ei       = (const int*)d_in[1];
    const int*   batch    = (const int*)d_in[2];
    const float* W1       = (const float*)d_in[3];
    const float* b1       = (const float*)d_in[4];
    const float* W2       = (const float*)d_in[5];
    const float* b2       = (const float*)d_in[6];
    const float* gin_eps  = (const float*)d_in[7];
    const float* gin_bias = (const float*)d_in[8];
    const float* gamma    = (const float*)d_in[9];
    const float* beta     = (const float*)d_in[10];
    const float* Wp1      = (const float*)d_in[11];
    const float* bp1      = (const float*)d_in[12];
    const float* Wp2      = (const float*)d_in[13];
    const float* bp2      = (const float*)d_in[14];
    float* out = (float*)d_out;

    // workspace layout
    float* bufA = (float*)d_ws;                             // N*64 (z3 even layers)
    float* bufB = bufA + (size_t)N_NODES * DF;              // N*64 (z3 odd layers)
    float* pooled = bufB + (size_t)N_NODES * DF;            // NGRAPH*LDIM
    float* hidden = pooled + (size_t)NGRAPH * LDIM;         // NGRAPH*LDIM
    float* scale = hidden + (size_t)NGRAPH * LDIM;          // 64
    float* shift = scale + 64;                              // 64
    float* idsc = shift + 64;                               // 64 (1.0)
    float* idsh = idsc + 64;                                // 64 (0.0)
    float* part_s = idsh + 64;                              // 64*NWT
    float* part_q = part_s + (size_t)64 * NWT;              // 64*NWT
    int* gstart = (int*)(part_q + (size_t)64 * NWT);        // NGRAPH+1
    int* deg  = gstart + NGRAPH + 1;                        // N
    int* cursor = deg + N_NODES;                            // N
    int* off  = cursor + N_NODES;                           // N+1
    int* colS = off + N_NODES + 1;                          // COLS_CAP
    int* blockSum = colS + COLS_CAP;                        // SCAN_BLOCKS
    int* blockOff = blockSum + SCAN_BLOCKS;                 // SCAN_BLOCKS
    short* Wpk = (short*)(blockOff + SCAN_BLOCKS + 1);      // 6*4096 bf16

    // ---- CSR build (padded) + graph segments + weight pack ----
    hipMemsetAsync(deg, 0, N_NODES * sizeof(int), stream);
    hipMemsetAsync(cursor, 0, N_NODES * sizeof(int), stream);
    hist_kernel<<<(N_EDGES + 255) / 256, 256, 0, stream>>>(ei, deg);
    block_sum_kernel<<<SCAN_BLOCKS, 1024, 0, stream>>>(deg, blockSum);
    scan_partials_kernel<<<1, 128, 0, stream>>>(blockSum, blockOff);
    scan_final_kernel<<<SCAN_BLOCKS, 1024, 0, stream>>>(deg, blockOff, off);
    fill_kernel<<<(N_EDGES + 255) / 256, 256, 0, stream>>>(ei, off, cursor, colS);
    pad_kernel<<<(N_NODES + 255) / 256, 256, 0, stream>>>(off, deg, colS);
    gstart_kernel<<<3, 256, 0, stream>>>(batch, gstart);
    init_id_kernel<<<1, 64, 0, stream>>>(idsc, idsh);
    pack_w_kernel<<<6, 256, 0, stream>>>(W1, W2, Wpk);

    const float* zprev = x;
    const float* sc_in = idsc;
    const float* sh_in = idsh;
    float* zbuf[2] = {bufA, bufB};
    for (int l = 0; l < 3; ++l) {
        float* zcur = zbuf[l & 1];
        gin_layer_kernel<<<GIN_GRID, 256, 0, stream>>>(
            zprev, sc_in, sh_in, off, deg, colS, zcur,
            Wpk + (size_t)l * 8192,
            b1 + l * 64, b2 + l * 64, gin_eps + l, gin_bias + l * 64,
            part_s, part_q);

        stat_reduce_kernel<<<64, 256, 0, stream>>>(
            part_s, part_q, gamma + l * 64, beta + l * 64, scale, shift);

        pool_kernel<<<NGRAPH, 256, 0, stream>>>(
            zcur, scale, shift, gstart, pooled, l * 64);

        zprev = zcur;
        sc_in = scale;
        sh_in = shift;
    }

    proj_kernel<<<NGRAPH, LDIM, 0, stream>>>(pooled, Wp1, bp1, hidden, 1);
    proj_kernel<<<NGRAPH, LDIM, 0, stream>>>(hidden, Wp2, bp2, out, 0);
}